// Round 11
// baseline (220.085 us; speedup 1.0000x reference)
//
#include <hip/hip_runtime.h>
#include <float.h>
#include <math.h>

#define BINS 2048
#define DSTN 8
#define STEPF 1e-5f
#define NMM 2048          // minmax blocks
#define NHIST 512
#define MAXST 2048
#define NSEG 64
#define MINF 0x7fffffff
#define NT 1024           // k_search block size

struct Ws {
  unsigned int mm_done, ev_done;      // zeroed via hipMemsetAsync each call
  int nseg, mbot;
  int n_states;
  int pad0[3];
  float min_val, max_val, bin_width, safe_bw;
  float pmin[NMM];
  float pmax[NMM];
  unsigned int hist[BINS];
  float histf[BINS];
  float Atab[2052];
  int   mterm[2052];
  int4  segB4[NSEG];
  float norms[MAXST];
  int2  states[MAXST];
};

// ---------------- Pass 0: data-independent tables (STEP only; 1 block) ----------------
__global__ void __launch_bounds__(256) k_tables(Ws* __restrict__ ws) {
  __shared__ __align__(16) int4 sB4[NSEG], sA4[NSEG];
  __shared__ int segklo[NSEG];
  __shared__ int s_nsg, s_mbot, s_nsa;
  int t = threadIdx.x;
  const float S = STEPF;

  if (t == 0) {
    // ---- B binade-segment table (validated rounds 4-10) ----
    int sg = 0; float B = 1.0f; int m0 = 0; int mbot = MINF;
    while (sg < NSEG && B > 0.0f) {
      float Bn = B - S;
      if (Bn <= 0.0f) {
        sB4[sg] = make_int4(__float_as_int(B), __float_as_int(B - Bn), m0, 0);
        ++sg; mbot = m0 + 1; break;
      }
      float d = B - Bn;                  // exact (Sterbenz)
      unsigned bb = __float_as_uint(B);
      unsigned bid = bb & 0x7f800000u;
      if ((bb & 0x007fffffu) == 0u) bid -= 0x00800000u;
      float binlo = __uint_as_float(bid);
      float brel = B - binlo;
      int nn = (int)floor((double)brel / (double)d);
      if (nn < 0) nn = 0;
      if (nn >= 2) {                     // tie-alternation guard
        float B1 = B - d;
        float B2 = B1 - S;
        if (B1 - B2 != d) nn = 1;
      }
      sB4[sg] = make_int4(__float_as_int(B), __float_as_int(d), m0, nn);
      ++sg;
      float Blast = B - (float)nn * d;
      B = Blast - S;
      m0 += nn + 1;
      if (B <= 0.0f) { mbot = m0; break; }
    }
    s_nsg = sg; s_mbot = mbot;
    // ---- A binade-segment table (validated rounds 6-10) ----
    int sa = 0;
    sA4[sa++] = make_int4(__float_as_int(0.0f), __float_as_int(S), 0, 0);  // A[0]=0
    float A0 = S; int k0 = 1;
    while (sa < NSEG && k0 <= 2051) {
      float An = A0 + S;
      float d = An - A0;                 // exact
      unsigned ab = __float_as_uint(A0);
      unsigned abid = ab & 0x7f800000u;
      float binhi = __uint_as_float(abid + 0x00800000u);
      float brel = binhi - A0;
      int nn = (int)floorf(brel / d);
      if (nn < 0) nn = 0;
      while (nn >= 1 && !(A0 + (float)nn * d < binhi)) --nn;
      while (A0 + (float)(nn + 1) * d < binhi) ++nn;
      if (nn >= 2) {                     // tie-alternation guard
        float A1 = A0 + d;
        float A2 = A1 + S;
        if (A2 - A1 != d) nn = 1;
      }
      if (k0 + nn > 2051) nn = 2051 - k0;
      sA4[sa++] = make_int4(__float_as_int(A0), __float_as_int(d), k0, nn);
      float Alast = A0 + (float)nn * d;
      A0 = Alast + S;
      k0 += nn + 1;
    }
    s_nsa = sa;
  }
  __syncthreads();
  int nsg = s_nsg, mbot = s_mbot, nsa = s_nsa;

  for (int sg = 0; sg < nsa; ++sg) {
    int4 sv = sA4[sg];
    float A0v = __int_as_float(sv.x), dv = __int_as_float(sv.y);
    for (int i = t; i <= sv.w; i += 256) ws->Atab[sv.z + i] = A0v + (float)i * dv;
  }
  __syncthreads();
  {
    int okA = 1;
    for (int k = t; k < 2051; k += 256) okA &= (ws->Atab[k] + S == ws->Atab[k + 1]) ? 1 : 0;
    if (__syncthreads_and(okA) == 0) {
      if (t == 0) {
        float a = 0.0f; ws->Atab[0] = 0.0f;
        for (int k = 1; k < 2052; ++k) { a = a + S; ws->Atab[k] = a; }
      }
      __syncthreads();
    }
  }
  if (t < nsg) {
    int4 sv = sB4[t];
    float Bs = __int_as_float(sv.x), dd = __int_as_float(sv.y);
    float Bend = Bs - (float)sv.w * dd;
    int lo = 0, hi = 2052;
    while (lo < hi) { int mid = (lo + hi) >> 1; if (ws->Atab[mid] < Bend) lo = mid + 1; else hi = mid; }
    segklo[t] = lo;
    ws->segB4[t] = sv;
  }
  if (t == 0) { ws->nseg = nsg; ws->mbot = mbot; }
  __syncthreads();
  for (int sg = 0; sg < nsg; ++sg) {
    int lo = segklo[sg], hi = (sg ? segklo[sg - 1] : 2052);
    if (lo >= hi) continue;
    int4 sv = sB4[sg];
    float Bs = __int_as_float(sv.x), dd = __int_as_float(sv.y);
    int ms = sv.z, nn = sv.w;
    float rd = (dd > 0.0f) ? 1.0f / dd : 0.0f;
    for (int k = lo + t; k < hi; k += 256) {
      float a = ws->Atab[k];
      int i2 = (int)((Bs - a) * rd);
      if (i2 < 0) i2 = 0; if (i2 > nn) i2 = nn;
      while (i2 > 0 && Bs - (float)(i2 - 1) * dd <= a) --i2;
      while (i2 <= nn && Bs - (float)i2 * dd > a) ++i2;
      ws->mterm[k] = ms + i2;
    }
  }
  {
    int dhi = segklo[nsg - 1];
    for (int k = t; k < dhi; k += 256) ws->mterm[k] = mbot;
  }
}

// ---------------- Pass 1: min/max sweep — contiguous chunks, 8-deep loads ----------------
// __launch_bounds__(256,2): VGPR cap 128 so the 8 float4 loads stay in flight
// (round-10 post-mortem: default regalloc gave 16 VGPRs -> serialized loads,
// 1.5 TB/s latency-bound).
__global__ void __launch_bounds__(256, 2) k_minmax(const float* __restrict__ x, long long n,
                                                   Ws* __restrict__ ws) {
  __shared__ float smin[4], smax[4];
  __shared__ float redn[256], redx[256];
  __shared__ int amLast;
  int t = threadIdx.x;

  long long n4 = n >> 2;
  const float4* __restrict__ x4 = (const float4*)x;
  long long chunk = (n4 + NMM - 1) / NMM;
  long long end = (long long)(blockIdx.x + 1) * chunk;
  if (end > n4) end = n4;
  long long i = (long long)blockIdx.x * chunk + t;
  float vmin = FLT_MAX, vmax = -FLT_MAX;

  for (; i + 7 * 256 < end; i += 8 * 256) {
    float4 v0 = x4[i];
    float4 v1 = x4[i + 256];
    float4 v2 = x4[i + 512];
    float4 v3 = x4[i + 768];
    float4 v4 = x4[i + 1024];
    float4 v5 = x4[i + 1280];
    float4 v6 = x4[i + 1536];
    float4 v7 = x4[i + 1792];
    float mn0 = fminf(fminf(v0.x, v0.y), fminf(v0.z, v0.w));
    float mn1 = fminf(fminf(v1.x, v1.y), fminf(v1.z, v1.w));
    float mn2 = fminf(fminf(v2.x, v2.y), fminf(v2.z, v2.w));
    float mn3 = fminf(fminf(v3.x, v3.y), fminf(v3.z, v3.w));
    float mn4 = fminf(fminf(v4.x, v4.y), fminf(v4.z, v4.w));
    float mn5 = fminf(fminf(v5.x, v5.y), fminf(v5.z, v5.w));
    float mn6 = fminf(fminf(v6.x, v6.y), fminf(v6.z, v6.w));
    float mn7 = fminf(fminf(v7.x, v7.y), fminf(v7.z, v7.w));
    float mx0 = fmaxf(fmaxf(v0.x, v0.y), fmaxf(v0.z, v0.w));
    float mx1 = fmaxf(fmaxf(v1.x, v1.y), fmaxf(v1.z, v1.w));
    float mx2 = fmaxf(fmaxf(v2.x, v2.y), fmaxf(v2.z, v2.w));
    float mx3 = fmaxf(fmaxf(v3.x, v3.y), fmaxf(v3.z, v3.w));
    float mx4 = fmaxf(fmaxf(v4.x, v4.y), fmaxf(v4.z, v4.w));
    float mx5 = fmaxf(fmaxf(v5.x, v5.y), fmaxf(v5.z, v5.w));
    float mx6 = fmaxf(fmaxf(v6.x, v6.y), fmaxf(v6.z, v6.w));
    float mx7 = fmaxf(fmaxf(v7.x, v7.y), fmaxf(v7.z, v7.w));
    vmin = fminf(vmin, fminf(fminf(fminf(mn0, mn1), fminf(mn2, mn3)),
                             fminf(fminf(mn4, mn5), fminf(mn6, mn7))));
    vmax = fmaxf(vmax, fmaxf(fmaxf(fmaxf(mx0, mx1), fmaxf(mx2, mx3)),
                             fmaxf(fmaxf(mx4, mx5), fmaxf(mx6, mx7))));
  }
  for (; i < end; i += 256) {
    float4 v = x4[i];
    vmin = fminf(vmin, fminf(fminf(v.x, v.y), fminf(v.z, v.w)));
    vmax = fmaxf(vmax, fmaxf(fmaxf(v.x, v.y), fmaxf(v.z, v.w)));
  }
  // scalar tail (n % 4), handled by block 0
  if (blockIdx.x == 0) {
    int rem = (int)(n - (n4 << 2));
    if (t < rem) {
      float v = x[(n4 << 2) + t];
      vmin = fminf(vmin, v); vmax = fmaxf(vmax, v);
    }
  }

  for (int off = 32; off > 0; off >>= 1) {
    vmin = fminf(vmin, __shfl_down(vmin, off));
    vmax = fmaxf(vmax, __shfl_down(vmax, off));
  }
  int wid = t >> 6;
  if ((t & 63) == 0) { smin[wid] = vmin; smax[wid] = vmax; }
  __syncthreads();
  if (t == 0) {
    float a = smin[0], b = smax[0];
    for (int w = 1; w < 4; ++w) { a = fminf(a, smin[w]); b = fmaxf(b, smax[w]); }
    ws->pmin[blockIdx.x] = a; ws->pmax[blockIdx.x] = b;
    __threadfence();                      // thread-0 only: release pmin/pmax
    amLast = (atomicAdd(&ws->mm_done, 1u) == (unsigned)(NMM - 1)) ? 1 : 0;
  }
  __syncthreads();
  if (amLast) {
    __threadfence();                      // single block: acquire
    float fmn = FLT_MAX, fmx = -FLT_MAX;
    for (int q = t; q < NMM; q += 256) {
      fmn = fminf(fmn, ws->pmin[q]);
      fmx = fmaxf(fmx, ws->pmax[q]);
    }
    redn[t] = fmn; redx[t] = fmx;
    __syncthreads();
    for (int off = 128; off > 0; off >>= 1) {
      if (t < off) { redn[t] = fminf(redn[t], redn[t + off]); redx[t] = fmaxf(redx[t], redx[t + off]); }
      __syncthreads();
    }
    if (t == 0) {
      float mn = redn[0], mx = redx[0];
      ws->min_val = mn; ws->max_val = mx;
      float bw = (mx - mn) / (float)BINS;
      ws->bin_width = bw;
      ws->safe_bw = (bw == 0.0f) ? 1.0f : bw;
    }
    for (int q = t; q < BINS; q += 256) ws->hist[q] = 0u;
  }
}

// ---------------- Pass 2: histogram — contiguous chunks, 4-deep loads, exact division ----
__global__ void __launch_bounds__(256, 2) k_hist(const float* __restrict__ x, long long n,
                                                 Ws* __restrict__ ws) {
  __shared__ __align__(16) unsigned int lh[BINS * 4];
  for (int i = threadIdx.x; i < BINS * 4; i += 256) lh[i] = 0u;
  __syncthreads();
  float minv = ws->min_val;
  float sbw = ws->safe_bw;
  int sub = threadIdx.x & 3;
  int t = threadIdx.x;
  long long n4 = n >> 2;
  const float4* __restrict__ x4 = (const float4*)x;
  long long chunk = (n4 + NHIST - 1) / NHIST;
  long long end = (long long)(blockIdx.x + 1) * chunk;
  if (end > n4) end = n4;
  long long i = (long long)blockIdx.x * chunk + t;

  for (; i + 3 * 256 < end; i += 4 * 256) {
    float4 v0 = x4[i];
    float4 v1 = x4[i + 256];
    float4 v2 = x4[i + 512];
    float4 v3 = x4[i + 768];
    int a0 = min(BINS - 1, max(0, (int)floorf((v0.x - minv) / sbw)));
    int b0 = min(BINS - 1, max(0, (int)floorf((v0.y - minv) / sbw)));
    int c0 = min(BINS - 1, max(0, (int)floorf((v0.z - minv) / sbw)));
    int d0 = min(BINS - 1, max(0, (int)floorf((v0.w - minv) / sbw)));
    int a1 = min(BINS - 1, max(0, (int)floorf((v1.x - minv) / sbw)));
    int b1 = min(BINS - 1, max(0, (int)floorf((v1.y - minv) / sbw)));
    int c1 = min(BINS - 1, max(0, (int)floorf((v1.z - minv) / sbw)));
    int d1 = min(BINS - 1, max(0, (int)floorf((v1.w - minv) / sbw)));
    int a2 = min(BINS - 1, max(0, (int)floorf((v2.x - minv) / sbw)));
    int b2 = min(BINS - 1, max(0, (int)floorf((v2.y - minv) / sbw)));
    int c2 = min(BINS - 1, max(0, (int)floorf((v2.z - minv) / sbw)));
    int d2 = min(BINS - 1, max(0, (int)floorf((v2.w - minv) / sbw)));
    int a3 = min(BINS - 1, max(0, (int)floorf((v3.x - minv) / sbw)));
    int b3 = min(BINS - 1, max(0, (int)floorf((v3.y - minv) / sbw)));
    int c3 = min(BINS - 1, max(0, (int)floorf((v3.z - minv) / sbw)));
    int d3 = min(BINS - 1, max(0, (int)floorf((v3.w - minv) / sbw)));
    atomicAdd(&lh[(a0 << 2) | sub], 1u);
    atomicAdd(&lh[(b0 << 2) | sub], 1u);
    atomicAdd(&lh[(c0 << 2) | sub], 1u);
    atomicAdd(&lh[(d0 << 2) | sub], 1u);
    atomicAdd(&lh[(a1 << 2) | sub], 1u);
    atomicAdd(&lh[(b1 << 2) | sub], 1u);
    atomicAdd(&lh[(c1 << 2) | sub], 1u);
    atomicAdd(&lh[(d1 << 2) | sub], 1u);
    atomicAdd(&lh[(a2 << 2) | sub], 1u);
    atomicAdd(&lh[(b2 << 2) | sub], 1u);
    atomicAdd(&lh[(c2 << 2) | sub], 1u);
    atomicAdd(&lh[(d2 << 2) | sub], 1u);
    atomicAdd(&lh[(a3 << 2) | sub], 1u);
    atomicAdd(&lh[(b3 << 2) | sub], 1u);
    atomicAdd(&lh[(c3 << 2) | sub], 1u);
    atomicAdd(&lh[(d3 << 2) | sub], 1u);
  }
  for (; i < end; i += 256) {
    float4 v = x4[i];
    int a = min(BINS - 1, max(0, (int)floorf((v.x - minv) / sbw)));
    int b = min(BINS - 1, max(0, (int)floorf((v.y - minv) / sbw)));
    int c = min(BINS - 1, max(0, (int)floorf((v.z - minv) / sbw)));
    int d = min(BINS - 1, max(0, (int)floorf((v.w - minv) / sbw)));
    atomicAdd(&lh[(a << 2) | sub], 1u);
    atomicAdd(&lh[(b << 2) | sub], 1u);
    atomicAdd(&lh[(c << 2) | sub], 1u);
    atomicAdd(&lh[(d << 2) | sub], 1u);
  }
  if (blockIdx.x == 0) {
    int rem = (int)(n - (n4 << 2));
    if (t < rem) {
      int a = (int)floorf((x[(n4 << 2) + t] - minv) / sbw);
      a = min(BINS - 1, max(0, a));
      atomicAdd(&lh[(a << 2) | sub], 1u);
    }
  }
  __syncthreads();
  for (int q = threadIdx.x; q < BINS; q += 256) {
    uint4 v = *((const uint4*)lh + q);
    unsigned int c = v.x + v.y + v.z + v.w;
    if (c) atomicAdd(&ws->hist[q], c);
  }
}

// ---------------- Phase 3a: csum-dependent tables + zipper + parallel tail ----
// (validated rounds 7-10; tables prebuilt in k_tables)
__global__ void __launch_bounds__(NT) k_search(Ws* __restrict__ ws) {
  __shared__ __align__(16) float csum[BINS];
  __shared__ __align__(16) int2  ltmt[2052];
  __shared__ __align__(16) int   mcross[BINS];
  __shared__ __align__(16) int   chain[2052];
  __shared__ __align__(16) int2  ev[2049];
  __shared__ __align__(16) int4  sB4[NSEG];
  __shared__ int   segblo[NSEG];
  __shared__ float fwav[16];
  __shared__ int   ired[16], ired2[16];
  __shared__ int   pub_nc;
  __shared__ int   pub_mode, pub_j0, pub_sb, pub_mt, pub_nst0, pub_nfire, pub_clamp, pub_ntot;

  int t = threadIdx.x;
  int lane = t & 63, wid = t >> 6;

  if (t < NSEG) sB4[t] = ws->segB4[t];
  int nsg = ws->nseg;
  int mbot = ws->mbot;

  // ---- phase 0: cumsum (integer-exact under any association) ----
  float h0 = (float)ws->hist[2 * t];
  float h1 = (float)ws->hist[2 * t + 1];
  ws->histf[2 * t] = h0; ws->histf[2 * t + 1] = h1;
  float s = h0 + h1;
  float isc = s;
  #pragma unroll
  for (int off = 1; off < 64; off <<= 1) {
    float u = __shfl_up(isc, off);
    if (lane >= off) isc += u;
  }
  if (lane == 63) fwav[wid] = isc;
  __syncthreads();
  if (t < 16) {
    float v = fwav[t];
    #pragma unroll
    for (int off = 1; off < 16; off <<= 1) {
      float u = __shfl_up(v, off, 16);
      if ((t & 15) >= off) v += u;
    }
    fwav[t] = v;
  }
  __syncthreads();
  {
    float base = wid ? fwav[wid - 1] : 0.0f;
    float excl = base + (isc - s);
    csum[2 * t] = excl + h0;
    csum[2 * t + 1] = excl + s;
  }
  __syncthreads();

  const float T = csum[BINS - 1];
  const float rcpT = 1.0f / T;

  // ---- phase 2a: ltab binary searches (3-wide) + mterm load ----
  {
    int lov[3], hiv[3];
    float av1[3];
    #pragma unroll
    for (int i = 0; i < 3; ++i) {
      int k = t + NT * i;
      bool has = (k <= 2050);
      lov[i] = 0; hiv[i] = has ? BINS : 0;
      av1[i] = has ? ws->Atab[k + 1] * T : 0.0f;
    }
    #pragma unroll
    for (int lev = 0; lev < 12; ++lev) {
      #pragma unroll
      for (int i = 0; i < 3; ++i) {
        bool act = lov[i] < hiv[i];
        int mid = act ? ((lov[i] + hiv[i]) >> 1) : 0;
        float cv = csum[mid];
        bool g = act && (cv < av1[i]);
        lov[i] = g ? (mid + 1) : lov[i];
        hiv[i] = (act && !g) ? mid : hiv[i];
      }
    }
    #pragma unroll
    for (int i = 0; i < 3; ++i) {
      int k = t + NT * i;
      if (k < 2052) ltmt[k] = make_int2((k <= 2050) ? lov[i] : BINS, ws->mterm[k]);
    }
  }
  // ---- per-segment b-range bounds ----
  if (t < nsg) {
    int4 sv = sB4[t];
    float Bs = __int_as_float(sv.x), dd = __int_as_float(sv.y);
    float Bend = Bs - (float)sv.w * dd;
    float vt = Bend * T;
    int lo = 0, hi = BINS;
    while (lo < hi) { int mid = (lo + hi) >> 1; if (!(csum[mid] > vt)) lo = mid + 1; else hi = mid; }
    segblo[t] = lo;
  }
  __syncthreads();

  // ---- phase 2c: mcross via range inversion ----
  for (int sg = 0; sg < nsg; ++sg) {
    int lo = segblo[sg], hi = (sg ? segblo[sg - 1] : BINS);
    if (lo >= hi) continue;
    int4 sv = sB4[sg];
    float Bs = __int_as_float(sv.x), dd = __int_as_float(sv.y);
    int ms = sv.z, nn = sv.w;
    float rd = (dd > 0.0f) ? 1.0f / dd : 0.0f;
    for (int b = lo + t; b < hi; b += NT) {
      float c = csum[b];
      int i2 = (int)((Bs - c * rcpT) * rd);
      if (i2 < 0) i2 = 0; if (i2 > nn) i2 = nn;
      while (i2 > 0 && (Bs - (float)(i2 - 1) * dd) * T < c) --i2;
      while (i2 <= nn && !((Bs - (float)i2 * dd) * T < c)) ++i2;
      mcross[b] = ms + i2 - 1;
    }
  }
  {
    int dhi = segblo[nsg - 1];
    for (int b = t; b < dhi; b += NT) {
      float c = csum[b];
      mcross[b] = (c > 0.0f) ? ((mbot == MINF) ? MINF : (mbot - 1)) : MINF;
    }
  }
  __syncthreads();

  // ---- phase 3: run-endpoint ranks (wave-scan suffix count) + scatter chain ----
  {
    int b0 = 2 * t;
    int m0v = mcross[b0], m1v = mcross[b0 + 1];
    int mnext = (t < NT - 1) ? mcross[b0 + 2] : 0;
    bool e0b = (m0v != m1v);
    bool e1b = (b0 + 1 == BINS - 1) || (m1v != mnext);
    int cnt = (e0b ? 1 : 0) + (e1b ? 1 : 0);
    int inc = cnt;
    #pragma unroll
    for (int off = 1; off < 64; off <<= 1) {
      int u = __shfl_up(inc, off);
      if (lane >= off) inc += u;
    }
    if (lane == 63) ired[wid] = inc;
    __syncthreads();
    if (t < 16) {
      int v = ired[t];
      #pragma unroll
      for (int off = 1; off < 16; off <<= 1) {
        int u = __shfl_up(v, off, 16);
        if ((t & 15) >= off) v += u;
      }
      ired[t] = v;
    }
    __syncthreads();
    int base = wid ? ired[wid - 1] : 0;
    int incl_t = base + inc;
    int total = ired[15];
    int running = total - incl_t;
    if (e1b) { ++running; chain[running - 1] = b0 + 1; }
    if (e0b) { ++running; chain[running - 1] = b0; }
    if (t == 0) pub_nc = total;
  }
  __syncthreads();

  // ---- phase 4: parallel event list ----
  int NC = pub_nc;
  for (int j = 1 + t; j <= NC; j += NT) {
    ev[j] = make_int2(mcross[chain[j - 1]], (j < NC) ? chain[j] : -1);
  }
  if (t == 0 && NC < 2048) ev[NC + 1] = make_int2(MINF, -1);
  __syncthreads();

  // ---- phase 5: short serial zipper ----
  if (t == 0) {
    int k = 0, sb = 0, eb = BINS - 1, m = 0, j = 1, nst = 0;
    int2 lm0 = ltmt[0], lm1 = ltmt[1], lm2 = ltmt[2];
    int2 e0 = ev[1], e1 = ev[2], e2 = ev[3];
    int mode = 0;
    int guard = 0;
    pub_j0 = 0; pub_sb = 0; pub_mt = 0;
    while (++guard < 6000) {
      int lpos = lm0.x, mt = lm0.y;
      int mc = e0.x, ne = e0.y;
      int l = min(lpos, eb);
      int pl = l - sb;
      if (pl <= 0) { mode = 1; pub_j0 = j; pub_sb = sb; pub_mt = mt; break; }  // left frozen forever
      if (m >= mt) break;                               // alpha >= beta
      bool coin = (m == mc);
      int nec = max(ne, sb);
      int pr = eb - nec;
      bool fl = !coin || (pl > pr);
      if (fl) {
        sb = l; ++k;
        if (nst < MAXST) ws->states[nst] = make_int2(sb, eb);
        ++nst;
        if (sb >= eb) break;
        lm0 = lm1; lm1 = lm2; lm2 = ltmt[min(k + 2, 2051)];
      } else {
        eb = nec; m = mc + 1; ++j;
        if (nst < MAXST) ws->states[nst] = make_int2(sb, eb);
        ++nst;
        if (sb >= eb) break;
        e0 = e1; e1 = e2; e2 = ev[min(j + 2, 2048)];
      }
    }
    pub_mode = mode;
    pub_nst0 = (nst < MAXST) ? nst : MAXST;
  }
  __syncthreads();

  // ---- phase 6: parallel tail emission ----
  int mode = pub_mode;
  int nst0 = pub_nst0;
  if (mode == 1) {
    int j0 = pub_j0, sbF = pub_sb, mtF = pub_mt;
    int locA = NC + 1, locB = NC + 1;
    for (int j = j0 + t; j <= NC; j += NT) {
      int2 e = ev[j];
      if (e.x >= mtF && j < locA) locA = j;   // includes MINF sentinels
      if (e.y <= sbF && j < locB) locB = j;
    }
    #pragma unroll
    for (int off = 32; off > 0; off >>= 1) {
      locA = min(locA, __shfl_down(locA, off));
      locB = min(locB, __shfl_down(locB, off));
    }
    if (lane == 0) { ired[wid] = locA; ired2[wid] = locB; }
    __syncthreads();
    if (t == 0) {
      int jA = NC + 1, jB = NC + 1;
      for (int w = 0; w < 16; ++w) { jA = min(jA, ired[w]); jB = min(jB, ired2[w]); }
      int nfire, clampLast;
      if (jB < jA) { nfire = jB - j0 + 1; clampLast = 1; }
      else         { nfire = jA - j0;     clampLast = 0; }
      if (nfire < 0) nfire = 0;
      int ntot = nst0 + nfire;
      if (ntot > MAXST) ntot = MAXST;
      pub_nfire = nfire; pub_clamp = clampLast; pub_ntot = ntot;
    }
    __syncthreads();
    int nfire = pub_nfire, clampLast = pub_clamp;
    for (int i = t; i < nfire; i += NT) {
      int idx = nst0 + i;
      if (idx < MAXST) {
        int y = ev[j0 + i].y;
        ws->states[idx] = make_int2(sbF, (clampLast && i == nfire - 1) ? sbF : y);
      }
    }
    if (t == 0) ws->n_states = pub_ntot;
  } else {
    if (t == 0) ws->n_states = nst0;
  }
}

// ---------------- Phase 3b: evaluate quantization error for all states ----------------
__global__ void __launch_bounds__(256) k_eval(Ws* __restrict__ ws) {
  int i = blockIdx.x;
  if (i >= ws->n_states) return;
  int2 st = ws->states[i];
  float bw = ws->bin_width;
  float cntf = (float)(st.y - st.x + 1);
  float w = bw * cntf / (float)DSTN;
  int t = threadIdx.x;
  if (w == 0.0f) {
    if (t == 0) ws->norms[i] = 0.0f;
    return;
  }
  float hw = 0.5f * w;
  float hw3 = hw * hw * hw;
  float nsb = (float)st.x;
  float sum = 0.0f;
  #pragma unroll
  for (int k = 0; k < 8; ++k) {
    int j = t + 256 * k;
    float h = ws->histf[j];
    float begin = ((float)j - nsb) * bw;
    float end = begin + bw;
    float db = fminf(fmaxf(floorf(begin / w), 0.0f), (float)(DSTN - 1));
    float de = fminf(fmaxf(floorf(end / w), 0.0f), (float)(DSTN - 1));
    float density = h / bw;
    float dbc = (db + 0.5f) * w;
    float a1 = begin - dbc;
    float n1 = density * (hw3 - a1 * a1 * a1) / 3.0f;
    float nmid = density * (hw3 + hw3) / 3.0f;
    float dec = de * w + hw;
    float a3 = end - dec;
    float n3 = density * (a3 * a3 * a3 + hw3) / 3.0f;
    sum += n1 + (de - db - 1.0f) * nmid + n3;
  }
  __shared__ float red[256];
  red[t] = sum;
  __syncthreads();
  for (int off = 128; off > 0; off >>= 1) {
    if (t < off) red[t] += red[t + off];
    __syncthreads();
  }
  if (t == 0) ws->norms[i] = red[0];
}

// ---------------- Phase 3c: first norm increase -> final range ----------------
__global__ void __launch_bounds__(256) k_final(Ws* __restrict__ ws, float* __restrict__ out) {
  __shared__ int sbrk[256];
  int N = ws->n_states;
  int t = threadIdx.x;
  int loc = MINF;
  for (int i = t + 1; i < N; i += 256) {
    if (ws->norms[i] > ws->norms[i - 1]) loc = min(loc, i);
  }
  sbrk[t] = loc;
  __syncthreads();
  for (int off = 128; off > 0; off >>= 1) {
    if (t < off) sbrk[t] = min(sbrk[t], sbrk[t + off]);
    __syncthreads();
  }
  if (t == 0) {
    int sb, eb;
    if (N == 0) { sb = 0; eb = BINS - 1; }
    else {
      int ib = sbrk[0];
      int fi = (ib != MINF) ? (ib - 1) : (N - 1);
      int2 st = ws->states[fi];
      sb = st.x; eb = st.y;
    }
    float minv = ws->min_val, bw = ws->bin_width;
    out[0] = minv + bw * (float)sb;
    out[1] = minv + bw * (float)(eb + 1);
  }
}

extern "C" void kernel_launch(void* const* d_in, const int* in_sizes, int n_in,
                              void* d_out, int out_size, void* d_ws, size_t ws_size,
                              hipStream_t stream) {
  const float* x = (const float*)d_in[0];
  long long n = (long long)in_sizes[0];
  Ws* ws = (Ws*)d_ws;
  float* out = (float*)d_out;

  hipMemsetAsync(d_ws, 0, 8, stream);   // zero mm_done / ev_done tickets
  k_tables<<<1, 256, 0, stream>>>(ws);
  k_minmax<<<NMM, 256, 0, stream>>>(x, n, ws);
  k_hist<<<NHIST, 256, 0, stream>>>(x, n, ws);
  k_search<<<1, NT, 0, stream>>>(ws);
  k_eval<<<MAXST, 256, 0, stream>>>(ws);
  k_final<<<1, 256, 0, stream>>>(ws, out);
}

// Round 13
// 198.494 us; speedup vs baseline: 1.1088x; 1.1088x over previous
//
#include <hip/hip_runtime.h>
#include <float.h>
#include <math.h>

#define BINS 2048
#define DSTN 8
#define STEPF 1e-5f
#define NMM 2048          // minmax sweep blocks (+1 table block)
#define NHIST 512
#define MAXST 2048
#define NSEG 64
#define MINF 0x7fffffff
#define NT 1024           // k_search block size

// keep-alive: scalar input-only operands force all loads issued before this point
#define F4(v) "v"(v.x), "v"(v.y), "v"(v.z), "v"(v.w)
#define KEEP8(a,b,c,d,e,f,g,h) asm volatile("" :: F4(a),F4(b),F4(c),F4(d),F4(e),F4(f),F4(g),F4(h))
#define KEEP4(a,b,c,d) asm volatile("" :: F4(a),F4(b),F4(c),F4(d))

struct Ws {
  unsigned int mm_done, ev_done;      // zeroed via hipMemsetAsync each call
  int nseg, mbot;
  int n_states;
  int pad0[3];
  float min_val, max_val, bin_width, safe_bw;
  float pmin[NMM];
  float pmax[NMM];
  unsigned int hist[BINS];
  float histf[BINS];
  float Atab[2052];
  int   mterm[2052];
  int4  segB4[NSEG];
  float norms[MAXST];
  int2  states[MAXST];
};

// ---------------- Pass 1: min/max sweep (grid-stride, 8 loads in flight via
// keep-alive asm) + concurrent data-independent table build (block NMM) +
// last-block final reduce ----------------
__global__ void __launch_bounds__(256) k_minmax(const float* __restrict__ x, long long n,
                                                Ws* __restrict__ ws) {
  __shared__ float smin[4], smax[4];
  __shared__ float redn[256], redx[256];
  __shared__ __align__(16) int4 sB4[NSEG], sA4[NSEG];
  __shared__ int segklo[NSEG];
  __shared__ int s_nsg, s_mbot, s_nsa;
  __shared__ int amLast;
  int t = threadIdx.x;
  const float S = STEPF;

  if (blockIdx.x == NMM) {
    // ======== data-independent tables (concurrent with HBM sweep; validated r4-r11) ====
    if (t == 0) {
      int sg = 0; float B = 1.0f; int m0 = 0; int mbot = MINF;
      while (sg < NSEG && B > 0.0f) {
        float Bn = B - S;
        if (Bn <= 0.0f) {
          sB4[sg] = make_int4(__float_as_int(B), __float_as_int(B - Bn), m0, 0);
          ++sg; mbot = m0 + 1; break;
        }
        float d = B - Bn;                  // exact (Sterbenz)
        unsigned bb = __float_as_uint(B);
        unsigned bid = bb & 0x7f800000u;
        if ((bb & 0x007fffffu) == 0u) bid -= 0x00800000u;
        float binlo = __uint_as_float(bid);
        float brel = B - binlo;
        int nn = (int)floor((double)brel / (double)d);
        if (nn < 0) nn = 0;
        if (nn >= 2) {                     // tie-alternation guard
          float B1 = B - d;
          float B2 = B1 - S;
          if (B1 - B2 != d) nn = 1;
        }
        sB4[sg] = make_int4(__float_as_int(B), __float_as_int(d), m0, nn);
        ++sg;
        float Blast = B - (float)nn * d;
        B = Blast - S;
        m0 += nn + 1;
        if (B <= 0.0f) { mbot = m0; break; }
      }
      s_nsg = sg; s_mbot = mbot;
      int sa = 0;
      sA4[sa++] = make_int4(__float_as_int(0.0f), __float_as_int(S), 0, 0);  // A[0]=0
      float A0 = S; int k0 = 1;
      while (sa < NSEG && k0 <= 2051) {
        float An = A0 + S;
        float d = An - A0;                 // exact
        unsigned ab = __float_as_uint(A0);
        unsigned abid = ab & 0x7f800000u;
        float binhi = __uint_as_float(abid + 0x00800000u);
        float brel = binhi - A0;
        int nn = (int)floorf(brel / d);
        if (nn < 0) nn = 0;
        while (nn >= 1 && !(A0 + (float)nn * d < binhi)) --nn;
        while (A0 + (float)(nn + 1) * d < binhi) ++nn;
        if (nn >= 2) {                     // tie-alternation guard
          float A1 = A0 + d;
          float A2 = A1 + S;
          if (A2 - A1 != d) nn = 1;
        }
        if (k0 + nn > 2051) nn = 2051 - k0;
        sA4[sa++] = make_int4(__float_as_int(A0), __float_as_int(d), k0, nn);
        float Alast = A0 + (float)nn * d;
        A0 = Alast + S;
        k0 += nn + 1;
      }
      s_nsa = sa;
    }
    __syncthreads();
    int nsg = s_nsg, mbot = s_mbot, nsa = s_nsa;

    for (int sg = 0; sg < nsa; ++sg) {
      int4 sv = sA4[sg];
      float A0v = __int_as_float(sv.x), dv = __int_as_float(sv.y);
      for (int i = t; i <= sv.w; i += 256) ws->Atab[sv.z + i] = A0v + (float)i * dv;
    }
    __syncthreads();
    {
      int okA = 1;
      for (int k = t; k < 2051; k += 256) okA &= (ws->Atab[k] + S == ws->Atab[k + 1]) ? 1 : 0;
      if (__syncthreads_and(okA) == 0) {
        if (t == 0) {
          float a = 0.0f; ws->Atab[0] = 0.0f;
          for (int k = 1; k < 2052; ++k) { a = a + S; ws->Atab[k] = a; }
        }
        __syncthreads();
      }
    }
    if (t < nsg) {
      int4 sv = sB4[t];
      float Bs = __int_as_float(sv.x), dd = __int_as_float(sv.y);
      float Bend = Bs - (float)sv.w * dd;
      int lo = 0, hi = 2052;
      while (lo < hi) { int mid = (lo + hi) >> 1; if (ws->Atab[mid] < Bend) lo = mid + 1; else hi = mid; }
      segklo[t] = lo;
      ws->segB4[t] = sv;
    }
    if (t == 0) { ws->nseg = nsg; ws->mbot = mbot; }
    __syncthreads();
    for (int sg = 0; sg < nsg; ++sg) {
      int lo = segklo[sg], hi = (sg ? segklo[sg - 1] : 2052);
      if (lo >= hi) continue;
      int4 sv = sB4[sg];
      float Bs = __int_as_float(sv.x), dd = __int_as_float(sv.y);
      int ms = sv.z, nn = sv.w;
      float rd = (dd > 0.0f) ? 1.0f / dd : 0.0f;
      for (int k = lo + t; k < hi; k += 256) {
        float a = ws->Atab[k];
        int i2 = (int)((Bs - a) * rd);
        if (i2 < 0) i2 = 0; if (i2 > nn) i2 = nn;
        while (i2 > 0 && Bs - (float)(i2 - 1) * dd <= a) --i2;
        while (i2 <= nn && Bs - (float)i2 * dd > a) ++i2;
        ws->mterm[k] = ms + i2;
      }
    }
    {
      int dhi = segklo[nsg - 1];
      for (int k = t; k < dhi; k += 256) ws->mterm[k] = mbot;
    }
    return;
  }

  // ======== min/max sweep (blocks 0..NMM-1), grid-stride, MLP=8 ========
  long long n4 = n >> 2;
  const float4* __restrict__ x4 = (const float4*)x;
  const long long G = (long long)NMM * 256;      // grid stride in float4
  float vmin = FLT_MAX, vmax = -FLT_MAX;
  long long i = (long long)blockIdx.x * 256 + t;
  for (; i + 7 * G < n4; i += 8 * G) {
    float4 v0 = x4[i];
    float4 v1 = x4[i + G];
    float4 v2 = x4[i + 2 * G];
    float4 v3 = x4[i + 3 * G];
    float4 v4 = x4[i + 4 * G];
    float4 v5 = x4[i + 5 * G];
    float4 v6 = x4[i + 6 * G];
    float4 v7 = x4[i + 7 * G];
    KEEP8(v0, v1, v2, v3, v4, v5, v6, v7);       // all 8 loads in flight
    float mn0 = fminf(fminf(v0.x, v0.y), fminf(v0.z, v0.w));
    float mn1 = fminf(fminf(v1.x, v1.y), fminf(v1.z, v1.w));
    float mn2 = fminf(fminf(v2.x, v2.y), fminf(v2.z, v2.w));
    float mn3 = fminf(fminf(v3.x, v3.y), fminf(v3.z, v3.w));
    float mn4 = fminf(fminf(v4.x, v4.y), fminf(v4.z, v4.w));
    float mn5 = fminf(fminf(v5.x, v5.y), fminf(v5.z, v5.w));
    float mn6 = fminf(fminf(v6.x, v6.y), fminf(v6.z, v6.w));
    float mn7 = fminf(fminf(v7.x, v7.y), fminf(v7.z, v7.w));
    float mx0 = fmaxf(fmaxf(v0.x, v0.y), fmaxf(v0.z, v0.w));
    float mx1 = fmaxf(fmaxf(v1.x, v1.y), fmaxf(v1.z, v1.w));
    float mx2 = fmaxf(fmaxf(v2.x, v2.y), fmaxf(v2.z, v2.w));
    float mx3 = fmaxf(fmaxf(v3.x, v3.y), fmaxf(v3.z, v3.w));
    float mx4 = fmaxf(fmaxf(v4.x, v4.y), fmaxf(v4.z, v4.w));
    float mx5 = fmaxf(fmaxf(v5.x, v5.y), fmaxf(v5.z, v5.w));
    float mx6 = fmaxf(fmaxf(v6.x, v6.y), fmaxf(v6.z, v6.w));
    float mx7 = fmaxf(fmaxf(v7.x, v7.y), fmaxf(v7.z, v7.w));
    vmin = fminf(vmin, fminf(fminf(fminf(mn0, mn1), fminf(mn2, mn3)),
                             fminf(fminf(mn4, mn5), fminf(mn6, mn7))));
    vmax = fmaxf(vmax, fmaxf(fmaxf(fmaxf(mx0, mx1), fmaxf(mx2, mx3)),
                             fmaxf(fmaxf(mx4, mx5), fmaxf(mx6, mx7))));
  }
  for (; i < n4; i += G) {
    float4 v = x4[i];
    vmin = fminf(vmin, fminf(fminf(v.x, v.y), fminf(v.z, v.w)));
    vmax = fmaxf(vmax, fmaxf(fmaxf(v.x, v.y), fmaxf(v.z, v.w)));
  }
  for (long long q = (n4 << 2) + (long long)blockIdx.x * 256 + t; q < n; q += G) {
    float v = x[q];
    vmin = fminf(vmin, v); vmax = fmaxf(vmax, v);
  }

  for (int off = 32; off > 0; off >>= 1) {
    vmin = fminf(vmin, __shfl_down(vmin, off));
    vmax = fmaxf(vmax, __shfl_down(vmax, off));
  }
  int wid = t >> 6;
  if ((t & 63) == 0) { smin[wid] = vmin; smax[wid] = vmax; }
  __syncthreads();
  if (t == 0) {
    float a = smin[0], b = smax[0];
    for (int w = 1; w < 4; ++w) { a = fminf(a, smin[w]); b = fmaxf(b, smax[w]); }
    ws->pmin[blockIdx.x] = a; ws->pmax[blockIdx.x] = b;
    __threadfence();                      // thread-0 only: release pmin/pmax
    amLast = (atomicAdd(&ws->mm_done, 1u) == (unsigned)(NMM - 1)) ? 1 : 0;
  }
  __syncthreads();
  if (amLast) {
    __threadfence();                      // single block: acquire
    float fmn = FLT_MAX, fmx = -FLT_MAX;
    for (int q = t; q < NMM; q += 256) {
      fmn = fminf(fmn, ws->pmin[q]);
      fmx = fmaxf(fmx, ws->pmax[q]);
    }
    redn[t] = fmn; redx[t] = fmx;
    __syncthreads();
    for (int off = 128; off > 0; off >>= 1) {
      if (t < off) { redn[t] = fminf(redn[t], redn[t + off]); redx[t] = fmaxf(redx[t], redx[t + off]); }
      __syncthreads();
    }
    if (t == 0) {
      float mn = redn[0], mx = redx[0];
      ws->min_val = mn; ws->max_val = mx;
      float bw = (mx - mn) / (float)BINS;
      ws->bin_width = bw;
      ws->safe_bw = (bw == 0.0f) ? 1.0f : bw;
    }
    for (int q = t; q < BINS; q += 256) ws->hist[q] = 0u;
  }
}

// ---------------- Pass 2: histogram — grid-stride, 4 loads in flight, 4-way sub-hists,
// exact /sbw division semantics ----------------
__global__ void __launch_bounds__(256) k_hist(const float* __restrict__ x, long long n,
                                              Ws* __restrict__ ws) {
  __shared__ __align__(16) unsigned int lh[BINS * 4];
  for (int i = threadIdx.x; i < BINS * 4; i += 256) lh[i] = 0u;
  __syncthreads();
  float minv = ws->min_val;
  float sbw = ws->safe_bw;
  int sub = threadIdx.x & 3;
  int t = threadIdx.x;
  long long n4 = n >> 2;
  const float4* __restrict__ x4 = (const float4*)x;
  const long long G = (long long)NHIST * 256;
  long long i = (long long)blockIdx.x * 256 + t;

  for (; i + 3 * G < n4; i += 4 * G) {
    float4 v0 = x4[i];
    float4 v1 = x4[i + G];
    float4 v2 = x4[i + 2 * G];
    float4 v3 = x4[i + 3 * G];
    KEEP4(v0, v1, v2, v3);                       // 4 loads in flight
    int a0 = min(BINS - 1, max(0, (int)floorf((v0.x - minv) / sbw)));
    int b0 = min(BINS - 1, max(0, (int)floorf((v0.y - minv) / sbw)));
    int c0 = min(BINS - 1, max(0, (int)floorf((v0.z - minv) / sbw)));
    int d0 = min(BINS - 1, max(0, (int)floorf((v0.w - minv) / sbw)));
    int a1 = min(BINS - 1, max(0, (int)floorf((v1.x - minv) / sbw)));
    int b1 = min(BINS - 1, max(0, (int)floorf((v1.y - minv) / sbw)));
    int c1 = min(BINS - 1, max(0, (int)floorf((v1.z - minv) / sbw)));
    int d1 = min(BINS - 1, max(0, (int)floorf((v1.w - minv) / sbw)));
    int a2 = min(BINS - 1, max(0, (int)floorf((v2.x - minv) / sbw)));
    int b2 = min(BINS - 1, max(0, (int)floorf((v2.y - minv) / sbw)));
    int c2 = min(BINS - 1, max(0, (int)floorf((v2.z - minv) / sbw)));
    int d2 = min(BINS - 1, max(0, (int)floorf((v2.w - minv) / sbw)));
    int a3 = min(BINS - 1, max(0, (int)floorf((v3.x - minv) / sbw)));
    int b3 = min(BINS - 1, max(0, (int)floorf((v3.y - minv) / sbw)));
    int c3 = min(BINS - 1, max(0, (int)floorf((v3.z - minv) / sbw)));
    int d3 = min(BINS - 1, max(0, (int)floorf((v3.w - minv) / sbw)));
    atomicAdd(&lh[(a0 << 2) | sub], 1u);
    atomicAdd(&lh[(b0 << 2) | sub], 1u);
    atomicAdd(&lh[(c0 << 2) | sub], 1u);
    atomicAdd(&lh[(d0 << 2) | sub], 1u);
    atomicAdd(&lh[(a1 << 2) | sub], 1u);
    atomicAdd(&lh[(b1 << 2) | sub], 1u);
    atomicAdd(&lh[(c1 << 2) | sub], 1u);
    atomicAdd(&lh[(d1 << 2) | sub], 1u);
    atomicAdd(&lh[(a2 << 2) | sub], 1u);
    atomicAdd(&lh[(b2 << 2) | sub], 1u);
    atomicAdd(&lh[(c2 << 2) | sub], 1u);
    atomicAdd(&lh[(d2 << 2) | sub], 1u);
    atomicAdd(&lh[(a3 << 2) | sub], 1u);
    atomicAdd(&lh[(b3 << 2) | sub], 1u);
    atomicAdd(&lh[(c3 << 2) | sub], 1u);
    atomicAdd(&lh[(d3 << 2) | sub], 1u);
  }
  for (; i < n4; i += G) {
    float4 v = x4[i];
    int a = min(BINS - 1, max(0, (int)floorf((v.x - minv) / sbw)));
    int b = min(BINS - 1, max(0, (int)floorf((v.y - minv) / sbw)));
    int c = min(BINS - 1, max(0, (int)floorf((v.z - minv) / sbw)));
    int d = min(BINS - 1, max(0, (int)floorf((v.w - minv) / sbw)));
    atomicAdd(&lh[(a << 2) | sub], 1u);
    atomicAdd(&lh[(b << 2) | sub], 1u);
    atomicAdd(&lh[(c << 2) | sub], 1u);
    atomicAdd(&lh[(d << 2) | sub], 1u);
  }
  for (long long q = (n4 << 2) + (long long)blockIdx.x * 256 + t; q < n; q += G) {
    int a = (int)floorf((x[q] - minv) / sbw);
    a = min(BINS - 1, max(0, a));
    atomicAdd(&lh[(a << 2) | sub], 1u);
  }
  __syncthreads();
  for (int q = threadIdx.x; q < BINS; q += 256) {
    uint4 v = *((const uint4*)lh + q);
    unsigned int c = v.x + v.y + v.z + v.w;
    if (c) atomicAdd(&ws->hist[q], c);
  }
}

// ---------------- Phase 3a: csum-dependent tables + zipper + parallel tail ----
// (validated rounds 7-11; static tables prebuilt concurrently in k_minmax's table block)
__global__ void __launch_bounds__(NT) k_search(Ws* __restrict__ ws) {
  __shared__ __align__(16) float csum[BINS];
  __shared__ __align__(16) int2  ltmt[2052];
  __shared__ __align__(16) int   mcross[BINS];
  __shared__ __align__(16) int   chain[2052];
  __shared__ __align__(16) int2  ev[2049];
  __shared__ __align__(16) int4  sB4[NSEG];
  __shared__ int   segblo[NSEG];
  __shared__ float fwav[16];
  __shared__ int   ired[16], ired2[16];
  __shared__ int   pub_nc;
  __shared__ int   pub_mode, pub_j0, pub_sb, pub_mt, pub_nst0, pub_nfire, pub_clamp, pub_ntot;

  int t = threadIdx.x;
  int lane = t & 63, wid = t >> 6;

  if (t < NSEG) sB4[t] = ws->segB4[t];
  int nsg = ws->nseg;
  int mbot = ws->mbot;

  // ---- phase 0: cumsum (integer-exact under any association) ----
  float h0 = (float)ws->hist[2 * t];
  float h1 = (float)ws->hist[2 * t + 1];
  ws->histf[2 * t] = h0; ws->histf[2 * t + 1] = h1;
  float s = h0 + h1;
  float isc = s;
  #pragma unroll
  for (int off = 1; off < 64; off <<= 1) {
    float u = __shfl_up(isc, off);
    if (lane >= off) isc += u;
  }
  if (lane == 63) fwav[wid] = isc;
  __syncthreads();
  if (t < 16) {
    float v = fwav[t];
    #pragma unroll
    for (int off = 1; off < 16; off <<= 1) {
      float u = __shfl_up(v, off, 16);
      if ((t & 15) >= off) v += u;
    }
    fwav[t] = v;
  }
  __syncthreads();
  {
    float base = wid ? fwav[wid - 1] : 0.0f;
    float excl = base + (isc - s);
    csum[2 * t] = excl + h0;
    csum[2 * t + 1] = excl + s;
  }
  __syncthreads();

  const float T = csum[BINS - 1];
  const float rcpT = 1.0f / T;

  // ---- phase 2a: ltab binary searches (3-wide) + mterm load ----
  {
    int lov[3], hiv[3];
    float av1[3];
    #pragma unroll
    for (int i = 0; i < 3; ++i) {
      int k = t + NT * i;
      bool has = (k <= 2050);
      lov[i] = 0; hiv[i] = has ? BINS : 0;
      av1[i] = has ? ws->Atab[k + 1] * T : 0.0f;
    }
    #pragma unroll
    for (int lev = 0; lev < 12; ++lev) {
      #pragma unroll
      for (int i = 0; i < 3; ++i) {
        bool act = lov[i] < hiv[i];
        int mid = act ? ((lov[i] + hiv[i]) >> 1) : 0;
        float cv = csum[mid];
        bool g = act && (cv < av1[i]);
        lov[i] = g ? (mid + 1) : lov[i];
        hiv[i] = (act && !g) ? mid : hiv[i];
      }
    }
    #pragma unroll
    for (int i = 0; i < 3; ++i) {
      int k = t + NT * i;
      if (k < 2052) ltmt[k] = make_int2((k <= 2050) ? lov[i] : BINS, ws->mterm[k]);
    }
  }
  // ---- per-segment b-range bounds ----
  if (t < nsg) {
    int4 sv = sB4[t];
    float Bs = __int_as_float(sv.x), dd = __int_as_float(sv.y);
    float Bend = Bs - (float)sv.w * dd;
    float vt = Bend * T;
    int lo = 0, hi = BINS;
    while (lo < hi) { int mid = (lo + hi) >> 1; if (!(csum[mid] > vt)) lo = mid + 1; else hi = mid; }
    segblo[t] = lo;
  }
  __syncthreads();

  // ---- phase 2c: mcross via range inversion ----
  for (int sg = 0; sg < nsg; ++sg) {
    int lo = segblo[sg], hi = (sg ? segblo[sg - 1] : BINS);
    if (lo >= hi) continue;
    int4 sv = sB4[sg];
    float Bs = __int_as_float(sv.x), dd = __int_as_float(sv.y);
    int ms = sv.z, nn = sv.w;
    float rd = (dd > 0.0f) ? 1.0f / dd : 0.0f;
    for (int b = lo + t; b < hi; b += NT) {
      float c = csum[b];
      int i2 = (int)((Bs - c * rcpT) * rd);
      if (i2 < 0) i2 = 0; if (i2 > nn) i2 = nn;
      while (i2 > 0 && (Bs - (float)(i2 - 1) * dd) * T < c) --i2;
      while (i2 <= nn && !((Bs - (float)i2 * dd) * T < c)) ++i2;
      mcross[b] = ms + i2 - 1;
    }
  }
  {
    int dhi = segblo[nsg - 1];
    for (int b = t; b < dhi; b += NT) {
      float c = csum[b];
      mcross[b] = (c > 0.0f) ? ((mbot == MINF) ? MINF : (mbot - 1)) : MINF;
    }
  }
  __syncthreads();

  // ---- phase 3: run-endpoint ranks (wave-scan suffix count) + scatter chain ----
  {
    int b0 = 2 * t;
    int m0v = mcross[b0], m1v = mcross[b0 + 1];
    int mnext = (t < NT - 1) ? mcross[b0 + 2] : 0;
    bool e0b = (m0v != m1v);
    bool e1b = (b0 + 1 == BINS - 1) || (m1v != mnext);
    int cnt = (e0b ? 1 : 0) + (e1b ? 1 : 0);
    int inc = cnt;
    #pragma unroll
    for (int off = 1; off < 64; off <<= 1) {
      int u = __shfl_up(inc, off);
      if (lane >= off) inc += u;
    }
    if (lane == 63) ired[wid] = inc;
    __syncthreads();
    if (t < 16) {
      int v = ired[t];
      #pragma unroll
      for (int off = 1; off < 16; off <<= 1) {
        int u = __shfl_up(v, off, 16);
        if ((t & 15) >= off) v += u;
      }
      ired[t] = v;
    }
    __syncthreads();
    int base = wid ? ired[wid - 1] : 0;
    int incl_t = base + inc;
    int total = ired[15];
    int running = total - incl_t;
    if (e1b) { ++running; chain[running - 1] = b0 + 1; }
    if (e0b) { ++running; chain[running - 1] = b0; }
    if (t == 0) pub_nc = total;
  }
  __syncthreads();

  // ---- phase 4: parallel event list ----
  int NC = pub_nc;
  for (int j = 1 + t; j <= NC; j += NT) {
    ev[j] = make_int2(mcross[chain[j - 1]], (j < NC) ? chain[j] : -1);
  }
  if (t == 0 && NC < 2048) ev[NC + 1] = make_int2(MINF, -1);
  __syncthreads();

  // ---- phase 5: short serial zipper ----
  if (t == 0) {
    int k = 0, sb = 0, eb = BINS - 1, m = 0, j = 1, nst = 0;
    int2 lm0 = ltmt[0], lm1 = ltmt[1], lm2 = ltmt[2];
    int2 e0 = ev[1], e1 = ev[2], e2 = ev[3];
    int mode = 0;
    int guard = 0;
    pub_j0 = 0; pub_sb = 0; pub_mt = 0;
    while (++guard < 6000) {
      int lpos = lm0.x, mt = lm0.y;
      int mc = e0.x, ne = e0.y;
      int l = min(lpos, eb);
      int pl = l - sb;
      if (pl <= 0) { mode = 1; pub_j0 = j; pub_sb = sb; pub_mt = mt; break; }  // left frozen forever
      if (m >= mt) break;                               // alpha >= beta
      bool coin = (m == mc);
      int nec = max(ne, sb);
      int pr = eb - nec;
      bool fl = !coin || (pl > pr);
      if (fl) {
        sb = l; ++k;
        if (nst < MAXST) ws->states[nst] = make_int2(sb, eb);
        ++nst;
        if (sb >= eb) break;
        lm0 = lm1; lm1 = lm2; lm2 = ltmt[min(k + 2, 2051)];
      } else {
        eb = nec; m = mc + 1; ++j;
        if (nst < MAXST) ws->states[nst] = make_int2(sb, eb);
        ++nst;
        if (sb >= eb) break;
        e0 = e1; e1 = e2; e2 = ev[min(j + 2, 2048)];
      }
    }
    pub_mode = mode;
    pub_nst0 = (nst < MAXST) ? nst : MAXST;
  }
  __syncthreads();

  // ---- phase 6: parallel tail emission ----
  int mode = pub_mode;
  int nst0 = pub_nst0;
  if (mode == 1) {
    int j0 = pub_j0, sbF = pub_sb, mtF = pub_mt;
    int locA = NC + 1, locB = NC + 1;
    for (int j = j0 + t; j <= NC; j += NT) {
      int2 e = ev[j];
      if (e.x >= mtF && j < locA) locA = j;   // includes MINF sentinels
      if (e.y <= sbF && j < locB) locB = j;
    }
    #pragma unroll
    for (int off = 32; off > 0; off >>= 1) {
      locA = min(locA, __shfl_down(locA, off));
      locB = min(locB, __shfl_down(locB, off));
    }
    if (lane == 0) { ired[wid] = locA; ired2[wid] = locB; }
    __syncthreads();
    if (t == 0) {
      int jA = NC + 1, jB = NC + 1;
      for (int w = 0; w < 16; ++w) { jA = min(jA, ired[w]); jB = min(jB, ired2[w]); }
      int nfire, clampLast;
      if (jB < jA) { nfire = jB - j0 + 1; clampLast = 1; }
      else         { nfire = jA - j0;     clampLast = 0; }
      if (nfire < 0) nfire = 0;
      int ntot = nst0 + nfire;
      if (ntot > MAXST) ntot = MAXST;
      pub_nfire = nfire; pub_clamp = clampLast; pub_ntot = ntot;
    }
    __syncthreads();
    int nfire = pub_nfire, clampLast = pub_clamp;
    for (int i = t; i < nfire; i += NT) {
      int idx = nst0 + i;
      if (idx < MAXST) {
        int y = ev[j0 + i].y;
        ws->states[idx] = make_int2(sbF, (clampLast && i == nfire - 1) ? sbF : y);
      }
    }
    if (t == 0) ws->n_states = pub_ntot;
  } else {
    if (t == 0) ws->n_states = nst0;
  }
}

// ---------------- Phase 3b: evaluate quantization error for all states ----------------
__global__ void __launch_bounds__(256) k_eval(Ws* __restrict__ ws) {
  int i = blockIdx.x;
  if (i >= ws->n_states) return;
  int2 st = ws->states[i];
  float bw = ws->bin_width;
  float cntf = (float)(st.y - st.x + 1);
  float w = bw * cntf / (float)DSTN;
  int t = threadIdx.x;
  if (w == 0.0f) {
    if (t == 0) ws->norms[i] = 0.0f;
    return;
  }
  float hw = 0.5f * w;
  float hw3 = hw * hw * hw;
  float nsb = (float)st.x;
  float sum = 0.0f;
  #pragma unroll
  for (int k = 0; k < 8; ++k) {
    int j = t + 256 * k;
    float h = ws->histf[j];
    float begin = ((float)j - nsb) * bw;
    float end = begin + bw;
    float db = fminf(fmaxf(floorf(begin / w), 0.0f), (float)(DSTN - 1));
    float de = fminf(fmaxf(floorf(end / w), 0.0f), (float)(DSTN - 1));
    float density = h / bw;
    float dbc = (db + 0.5f) * w;
    float a1 = begin - dbc;
    float n1 = density * (hw3 - a1 * a1 * a1) / 3.0f;
    float nmid = density * (hw3 + hw3) / 3.0f;
    float dec = de * w + hw;
    float a3 = end - dec;
    float n3 = density * (a3 * a3 * a3 + hw3) / 3.0f;
    sum += n1 + (de - db - 1.0f) * nmid + n3;
  }
  __shared__ float red[256];
  red[t] = sum;
  __syncthreads();
  for (int off = 128; off > 0; off >>= 1) {
    if (t < off) red[t] += red[t + off];
    __syncthreads();
  }
  if (t == 0) ws->norms[i] = red[0];
}

// ---------------- Phase 3c: first norm increase -> final range ----------------
__global__ void __launch_bounds__(256) k_final(Ws* __restrict__ ws, float* __restrict__ out) {
  __shared__ int sbrk[256];
  int N = ws->n_states;
  int t = threadIdx.x;
  int loc = MINF;
  for (int i = t + 1; i < N; i += 256) {
    if (ws->norms[i] > ws->norms[i - 1]) loc = min(loc, i);
  }
  sbrk[t] = loc;
  __syncthreads();
  for (int off = 128; off > 0; off >>= 1) {
    if (t < off) sbrk[t] = min(sbrk[t], sbrk[t + off]);
    __syncthreads();
  }
  if (t == 0) {
    int sb, eb;
    if (N == 0) { sb = 0; eb = BINS - 1; }
    else {
      int ib = sbrk[0];
      int fi = (ib != MINF) ? (ib - 1) : (N - 1);
      int2 st = ws->states[fi];
      sb = st.x; eb = st.y;
    }
    float minv = ws->min_val, bw = ws->bin_width;
    out[0] = minv + bw * (float)sb;
    out[1] = minv + bw * (float)(eb + 1);
  }
}

extern "C" void kernel_launch(void* const* d_in, const int* in_sizes, int n_in,
                              void* d_out, int out_size, void* d_ws, size_t ws_size,
                              hipStream_t stream) {
  const float* x = (const float*)d_in[0];
  long long n = (long long)in_sizes[0];
  Ws* ws = (Ws*)d_ws;
  float* out = (float*)d_out;

  (void)hipMemsetAsync(d_ws, 0, 8, stream);   // zero mm_done / ev_done tickets
  k_minmax<<<NMM + 1, 256, 0, stream>>>(x, n, ws);
  k_hist<<<NHIST, 256, 0, stream>>>(x, n, ws);
  k_search<<<1, NT, 0, stream>>>(ws);
  k_eval<<<MAXST, 256, 0, stream>>>(ws);
  k_final<<<1, 256, 0, stream>>>(ws, out);
}

// Round 14
// 157.220 us; speedup vs baseline: 1.3999x; 1.2625x over previous
//
#include <hip/hip_runtime.h>
#include <float.h>
#include <math.h>

#define BINS 2048
#define DSTN 8
#define STEPF 1e-5f
#define NMM 1024          // minmax partial blocks
#define NHIST 512
#define MAXST 2048
#define NSEG 64
#define MINF 0x7fffffff
#define NT 1024           // k_search block size

struct Ws {
  int nseg, mbot;
  int n_states;
  int pad0[5];
  float min_val, max_val, bin_width, safe_bw;
  float pmin[NMM];
  float pmax[NMM];
  unsigned int hist[BINS];
  float histf[BINS];
  float Atab[2052];
  int   mterm[2052];
  int4  segB4[NSEG];
  float norms[MAXST];
  int2  states[MAXST];
};

// ---------------- Pass 0: data-independent tables (STEP only; 1 block; validated) ----
__global__ void __launch_bounds__(256) k_tables(Ws* __restrict__ ws) {
  __shared__ __align__(16) int4 sB4[NSEG], sA4[NSEG];
  __shared__ int segklo[NSEG];
  __shared__ int s_nsg, s_mbot, s_nsa;
  int t = threadIdx.x;
  const float S = STEPF;

  if (t == 0) {
    // ---- B binade-segment table (validated rounds 4-13) ----
    int sg = 0; float B = 1.0f; int m0 = 0; int mbot = MINF;
    while (sg < NSEG && B > 0.0f) {
      float Bn = B - S;
      if (Bn <= 0.0f) {
        sB4[sg] = make_int4(__float_as_int(B), __float_as_int(B - Bn), m0, 0);
        ++sg; mbot = m0 + 1; break;
      }
      float d = B - Bn;                  // exact (Sterbenz)
      unsigned bb = __float_as_uint(B);
      unsigned bid = bb & 0x7f800000u;
      if ((bb & 0x007fffffu) == 0u) bid -= 0x00800000u;
      float binlo = __uint_as_float(bid);
      float brel = B - binlo;
      int nn = (int)floor((double)brel / (double)d);
      if (nn < 0) nn = 0;
      if (nn >= 2) {                     // tie-alternation guard
        float B1 = B - d;
        float B2 = B1 - S;
        if (B1 - B2 != d) nn = 1;
      }
      sB4[sg] = make_int4(__float_as_int(B), __float_as_int(d), m0, nn);
      ++sg;
      float Blast = B - (float)nn * d;
      B = Blast - S;
      m0 += nn + 1;
      if (B <= 0.0f) { mbot = m0; break; }
    }
    s_nsg = sg; s_mbot = mbot;
    // ---- A binade-segment table (validated rounds 6-13) ----
    int sa = 0;
    sA4[sa++] = make_int4(__float_as_int(0.0f), __float_as_int(S), 0, 0);  // A[0]=0
    float A0 = S; int k0 = 1;
    while (sa < NSEG && k0 <= 2051) {
      float An = A0 + S;
      float d = An - A0;                 // exact
      unsigned ab = __float_as_uint(A0);
      unsigned abid = ab & 0x7f800000u;
      float binhi = __uint_as_float(abid + 0x00800000u);
      float brel = binhi - A0;
      int nn = (int)floorf(brel / d);
      if (nn < 0) nn = 0;
      while (nn >= 1 && !(A0 + (float)nn * d < binhi)) --nn;
      while (A0 + (float)(nn + 1) * d < binhi) ++nn;
      if (nn >= 2) {                     // tie-alternation guard
        float A1 = A0 + d;
        float A2 = A1 + S;
        if (A2 - A1 != d) nn = 1;
      }
      if (k0 + nn > 2051) nn = 2051 - k0;
      sA4[sa++] = make_int4(__float_as_int(A0), __float_as_int(d), k0, nn);
      float Alast = A0 + (float)nn * d;
      A0 = Alast + S;
      k0 += nn + 1;
    }
    s_nsa = sa;
  }
  __syncthreads();
  int nsg = s_nsg, mbot = s_mbot, nsa = s_nsa;

  for (int sg = 0; sg < nsa; ++sg) {
    int4 sv = sA4[sg];
    float A0v = __int_as_float(sv.x), dv = __int_as_float(sv.y);
    for (int i = t; i <= sv.w; i += 256) ws->Atab[sv.z + i] = A0v + (float)i * dv;
  }
  __syncthreads();
  {
    int okA = 1;
    for (int k = t; k < 2051; k += 256) okA &= (ws->Atab[k] + S == ws->Atab[k + 1]) ? 1 : 0;
    if (__syncthreads_and(okA) == 0) {
      if (t == 0) {
        float a = 0.0f; ws->Atab[0] = 0.0f;
        for (int k = 1; k < 2052; ++k) { a = a + S; ws->Atab[k] = a; }
      }
      __syncthreads();
    }
  }
  if (t < nsg) {
    int4 sv = sB4[t];
    float Bs = __int_as_float(sv.x), dd = __int_as_float(sv.y);
    float Bend = Bs - (float)sv.w * dd;
    int lo = 0, hi = 2052;
    while (lo < hi) { int mid = (lo + hi) >> 1; if (ws->Atab[mid] < Bend) lo = mid + 1; else hi = mid; }
    segklo[t] = lo;
    ws->segB4[t] = sv;
  }
  if (t == 0) { ws->nseg = nsg; ws->mbot = mbot; }
  __syncthreads();
  for (int sg = 0; sg < nsg; ++sg) {
    int lo = segklo[sg], hi = (sg ? segklo[sg - 1] : 2052);
    if (lo >= hi) continue;
    int4 sv = sB4[sg];
    float Bs = __int_as_float(sv.x), dd = __int_as_float(sv.y);
    int ms = sv.z, nn = sv.w;
    float rd = (dd > 0.0f) ? 1.0f / dd : 0.0f;
    for (int k = lo + t; k < hi; k += 256) {
      float a = ws->Atab[k];
      int i2 = (int)((Bs - a) * rd);
      if (i2 < 0) i2 = 0; if (i2 > nn) i2 = nn;
      while (i2 > 0 && Bs - (float)(i2 - 1) * dd <= a) --i2;
      while (i2 <= nn && Bs - (float)i2 * dd > a) ++i2;
      ws->mterm[k] = ms + i2;
    }
  }
  {
    int dhi = segklo[nsg - 1];
    for (int k = t; k < dhi; k += 256) ws->mterm[k] = mbot;
  }
}

// ---------------- Pass 1: block-partial min/max (round-1 structure, NO atomics/fences) ----
__global__ void __launch_bounds__(256) k_minmax(const float* __restrict__ x, long long n,
                                                Ws* __restrict__ ws) {
  long long n4 = n >> 2;
  float vmin = FLT_MAX, vmax = -FLT_MAX;
  const float4* __restrict__ x4 = (const float4*)x;
  long long stride = (long long)gridDim.x * blockDim.x;
  for (long long i = (long long)blockIdx.x * blockDim.x + threadIdx.x; i < n4; i += stride) {
    float4 v = x4[i];
    vmin = fminf(vmin, fminf(fminf(v.x, v.y), fminf(v.z, v.w)));
    vmax = fmaxf(vmax, fmaxf(fmaxf(v.x, v.y), fmaxf(v.z, v.w)));
  }
  for (long long i = (n4 << 2) + (long long)blockIdx.x * blockDim.x + threadIdx.x; i < n; i += stride) {
    float v = x[i];
    vmin = fminf(vmin, v); vmax = fmaxf(vmax, v);
  }
  for (int off = 32; off > 0; off >>= 1) {
    vmin = fminf(vmin, __shfl_down(vmin, off));
    vmax = fmaxf(vmax, __shfl_down(vmax, off));
  }
  __shared__ float smin[4], smax[4];
  int wid = threadIdx.x >> 6;
  if ((threadIdx.x & 63) == 0) { smin[wid] = vmin; smax[wid] = vmax; }
  __syncthreads();
  if (threadIdx.x == 0) {
    float a = smin[0], b = smax[0];
    int nw = (int)(blockDim.x >> 6);
    for (int w = 1; w < nw; ++w) { a = fminf(a, smin[w]); b = fmaxf(b, smax[w]); }
    ws->pmin[blockIdx.x] = a; ws->pmax[blockIdx.x] = b;
  }
}

// ---------------- Reduce partials, compute bin_width, zero hist (round-1 structure) ----
__global__ void __launch_bounds__(256) k_minmax_final(Ws* __restrict__ ws, int nparts) {
  __shared__ float smin[256], smax[256];
  int t = threadIdx.x;
  float vmin = FLT_MAX, vmax = -FLT_MAX;
  for (int i = t; i < nparts; i += 256) {
    vmin = fminf(vmin, ws->pmin[i]);
    vmax = fmaxf(vmax, ws->pmax[i]);
  }
  smin[t] = vmin; smax[t] = vmax;
  __syncthreads();
  for (int off = 128; off > 0; off >>= 1) {
    if (t < off) { smin[t] = fminf(smin[t], smin[t + off]); smax[t] = fmaxf(smax[t], smax[t + off]); }
    __syncthreads();
  }
  if (t == 0) {
    float mn = smin[0], mx = smax[0];
    ws->min_val = mn; ws->max_val = mx;
    float bw = (mx - mn) / (float)BINS;
    ws->bin_width = bw;
    ws->safe_bw = (bw == 0.0f) ? 1.0f : bw;
  }
  for (int i = t; i < BINS; i += 256) ws->hist[i] = 0u;
}

// ---------------- Pass 2: histogram — 4-way LDS sub-hists, exact /sbw, grid-stride ----
__global__ void __launch_bounds__(256) k_hist(const float* __restrict__ x, long long n,
                                              Ws* __restrict__ ws) {
  __shared__ __align__(16) unsigned int lh[BINS * 4];
  for (int i = threadIdx.x; i < BINS * 4; i += 256) lh[i] = 0u;
  __syncthreads();
  float minv = ws->min_val;
  float sbw = ws->safe_bw;
  int sub = threadIdx.x & 3;
  long long n4 = n >> 2;
  const float4* __restrict__ x4 = (const float4*)x;
  long long stride = (long long)gridDim.x * blockDim.x;
  for (long long i = (long long)blockIdx.x * blockDim.x + threadIdx.x; i < n4; i += stride) {
    float4 v = x4[i];
    int a = min(BINS - 1, max(0, (int)floorf((v.x - minv) / sbw)));
    int b = min(BINS - 1, max(0, (int)floorf((v.y - minv) / sbw)));
    int c = min(BINS - 1, max(0, (int)floorf((v.z - minv) / sbw)));
    int d = min(BINS - 1, max(0, (int)floorf((v.w - minv) / sbw)));
    atomicAdd(&lh[(a << 2) | sub], 1u);
    atomicAdd(&lh[(b << 2) | sub], 1u);
    atomicAdd(&lh[(c << 2) | sub], 1u);
    atomicAdd(&lh[(d << 2) | sub], 1u);
  }
  for (long long i = (n4 << 2) + (long long)blockIdx.x * blockDim.x + threadIdx.x; i < n; i += stride) {
    int a = (int)floorf((x[i] - minv) / sbw);
    a = min(BINS - 1, max(0, a));
    atomicAdd(&lh[(a << 2) | sub], 1u);
  }
  __syncthreads();
  for (int q = threadIdx.x; q < BINS; q += 256) {
    uint4 v = *((const uint4*)lh + q);
    unsigned int c = v.x + v.y + v.z + v.w;
    if (c) atomicAdd(&ws->hist[q], c);
  }
}

// ---------------- Phase 3a: csum-dependent tables + zipper + parallel tail ----
// (validated rounds 7-13; static tables prebuilt in k_tables)
__global__ void __launch_bounds__(NT) k_search(Ws* __restrict__ ws) {
  __shared__ __align__(16) float csum[BINS];
  __shared__ __align__(16) int2  ltmt[2052];
  __shared__ __align__(16) int   mcross[BINS];
  __shared__ __align__(16) int   chain[2052];
  __shared__ __align__(16) int2  ev[2049];
  __shared__ __align__(16) int4  sB4[NSEG];
  __shared__ int   segblo[NSEG];
  __shared__ float fwav[16];
  __shared__ int   ired[16], ired2[16];
  __shared__ int   pub_nc;
  __shared__ int   pub_mode, pub_j0, pub_sb, pub_mt, pub_nst0, pub_nfire, pub_clamp, pub_ntot;

  int t = threadIdx.x;
  int lane = t & 63, wid = t >> 6;

  if (t < NSEG) sB4[t] = ws->segB4[t];
  int nsg = ws->nseg;
  int mbot = ws->mbot;

  // ---- phase 0: cumsum (integer-exact under any association) ----
  float h0 = (float)ws->hist[2 * t];
  float h1 = (float)ws->hist[2 * t + 1];
  ws->histf[2 * t] = h0; ws->histf[2 * t + 1] = h1;
  float s = h0 + h1;
  float isc = s;
  #pragma unroll
  for (int off = 1; off < 64; off <<= 1) {
    float u = __shfl_up(isc, off);
    if (lane >= off) isc += u;
  }
  if (lane == 63) fwav[wid] = isc;
  __syncthreads();
  if (t < 16) {
    float v = fwav[t];
    #pragma unroll
    for (int off = 1; off < 16; off <<= 1) {
      float u = __shfl_up(v, off, 16);
      if ((t & 15) >= off) v += u;
    }
    fwav[t] = v;
  }
  __syncthreads();
  {
    float base = wid ? fwav[wid - 1] : 0.0f;
    float excl = base + (isc - s);
    csum[2 * t] = excl + h0;
    csum[2 * t + 1] = excl + s;
  }
  __syncthreads();

  const float T = csum[BINS - 1];
  const float rcpT = 1.0f / T;

  // ---- phase 2a: ltab binary searches (3-wide) + mterm load ----
  {
    int lov[3], hiv[3];
    float av1[3];
    #pragma unroll
    for (int i = 0; i < 3; ++i) {
      int k = t + NT * i;
      bool has = (k <= 2050);
      lov[i] = 0; hiv[i] = has ? BINS : 0;
      av1[i] = has ? ws->Atab[k + 1] * T : 0.0f;
    }
    #pragma unroll
    for (int lev = 0; lev < 12; ++lev) {
      #pragma unroll
      for (int i = 0; i < 3; ++i) {
        bool act = lov[i] < hiv[i];
        int mid = act ? ((lov[i] + hiv[i]) >> 1) : 0;
        float cv = csum[mid];
        bool g = act && (cv < av1[i]);
        lov[i] = g ? (mid + 1) : lov[i];
        hiv[i] = (act && !g) ? mid : hiv[i];
      }
    }
    #pragma unroll
    for (int i = 0; i < 3; ++i) {
      int k = t + NT * i;
      if (k < 2052) ltmt[k] = make_int2((k <= 2050) ? lov[i] : BINS, ws->mterm[k]);
    }
  }
  // ---- per-segment b-range bounds ----
  if (t < nsg) {
    int4 sv = sB4[t];
    float Bs = __int_as_float(sv.x), dd = __int_as_float(sv.y);
    float Bend = Bs - (float)sv.w * dd;
    float vt = Bend * T;
    int lo = 0, hi = BINS;
    while (lo < hi) { int mid = (lo + hi) >> 1; if (!(csum[mid] > vt)) lo = mid + 1; else hi = mid; }
    segblo[t] = lo;
  }
  __syncthreads();

  // ---- phase 2c: mcross via range inversion ----
  for (int sg = 0; sg < nsg; ++sg) {
    int lo = segblo[sg], hi = (sg ? segblo[sg - 1] : BINS);
    if (lo >= hi) continue;
    int4 sv = sB4[sg];
    float Bs = __int_as_float(sv.x), dd = __int_as_float(sv.y);
    int ms = sv.z, nn = sv.w;
    float rd = (dd > 0.0f) ? 1.0f / dd : 0.0f;
    for (int b = lo + t; b < hi; b += NT) {
      float c = csum[b];
      int i2 = (int)((Bs - c * rcpT) * rd);
      if (i2 < 0) i2 = 0; if (i2 > nn) i2 = nn;
      while (i2 > 0 && (Bs - (float)(i2 - 1) * dd) * T < c) --i2;
      while (i2 <= nn && !((Bs - (float)i2 * dd) * T < c)) ++i2;
      mcross[b] = ms + i2 - 1;
    }
  }
  {
    int dhi = segblo[nsg - 1];
    for (int b = t; b < dhi; b += NT) {
      float c = csum[b];
      mcross[b] = (c > 0.0f) ? ((mbot == MINF) ? MINF : (mbot - 1)) : MINF;
    }
  }
  __syncthreads();

  // ---- phase 3: run-endpoint ranks (wave-scan suffix count) + scatter chain ----
  {
    int b0 = 2 * t;
    int m0v = mcross[b0], m1v = mcross[b0 + 1];
    int mnext = (t < NT - 1) ? mcross[b0 + 2] : 0;
    bool e0b = (m0v != m1v);
    bool e1b = (b0 + 1 == BINS - 1) || (m1v != mnext);
    int cnt = (e0b ? 1 : 0) + (e1b ? 1 : 0);
    int inc = cnt;
    #pragma unroll
    for (int off = 1; off < 64; off <<= 1) {
      int u = __shfl_up(inc, off);
      if (lane >= off) inc += u;
    }
    if (lane == 63) ired[wid] = inc;
    __syncthreads();
    if (t < 16) {
      int v = ired[t];
      #pragma unroll
      for (int off = 1; off < 16; off <<= 1) {
        int u = __shfl_up(v, off, 16);
        if ((t & 15) >= off) v += u;
      }
      ired[t] = v;
    }
    __syncthreads();
    int base = wid ? ired[wid - 1] : 0;
    int incl_t = base + inc;
    int total = ired[15];
    int running = total - incl_t;
    if (e1b) { ++running; chain[running - 1] = b0 + 1; }
    if (e0b) { ++running; chain[running - 1] = b0; }
    if (t == 0) pub_nc = total;
  }
  __syncthreads();

  // ---- phase 4: parallel event list ----
  int NC = pub_nc;
  for (int j = 1 + t; j <= NC; j += NT) {
    ev[j] = make_int2(mcross[chain[j - 1]], (j < NC) ? chain[j] : -1);
  }
  if (t == 0 && NC < 2048) ev[NC + 1] = make_int2(MINF, -1);
  __syncthreads();

  // ---- phase 5: short serial zipper ----
  if (t == 0) {
    int k = 0, sb = 0, eb = BINS - 1, m = 0, j = 1, nst = 0;
    int2 lm0 = ltmt[0], lm1 = ltmt[1], lm2 = ltmt[2];
    int2 e0 = ev[1], e1 = ev[2], e2 = ev[3];
    int mode = 0;
    int guard = 0;
    pub_j0 = 0; pub_sb = 0; pub_mt = 0;
    while (++guard < 6000) {
      int lpos = lm0.x, mt = lm0.y;
      int mc = e0.x, ne = e0.y;
      int l = min(lpos, eb);
      int pl = l - sb;
      if (pl <= 0) { mode = 1; pub_j0 = j; pub_sb = sb; pub_mt = mt; break; }  // left frozen forever
      if (m >= mt) break;                               // alpha >= beta
      bool coin = (m == mc);
      int nec = max(ne, sb);
      int pr = eb - nec;
      bool fl = !coin || (pl > pr);
      if (fl) {
        sb = l; ++k;
        if (nst < MAXST) ws->states[nst] = make_int2(sb, eb);
        ++nst;
        if (sb >= eb) break;
        lm0 = lm1; lm1 = lm2; lm2 = ltmt[min(k + 2, 2051)];
      } else {
        eb = nec; m = mc + 1; ++j;
        if (nst < MAXST) ws->states[nst] = make_int2(sb, eb);
        ++nst;
        if (sb >= eb) break;
        e0 = e1; e1 = e2; e2 = ev[min(j + 2, 2048)];
      }
    }
    pub_mode = mode;
    pub_nst0 = (nst < MAXST) ? nst : MAXST;
  }
  __syncthreads();

  // ---- phase 6: parallel tail emission ----
  int mode = pub_mode;
  int nst0 = pub_nst0;
  if (mode == 1) {
    int j0 = pub_j0, sbF = pub_sb, mtF = pub_mt;
    int locA = NC + 1, locB = NC + 1;
    for (int j = j0 + t; j <= NC; j += NT) {
      int2 e = ev[j];
      if (e.x >= mtF && j < locA) locA = j;   // includes MINF sentinels
      if (e.y <= sbF && j < locB) locB = j;
    }
    #pragma unroll
    for (int off = 32; off > 0; off >>= 1) {
      locA = min(locA, __shfl_down(locA, off));
      locB = min(locB, __shfl_down(locB, off));
    }
    if (lane == 0) { ired[wid] = locA; ired2[wid] = locB; }
    __syncthreads();
    if (t == 0) {
      int jA = NC + 1, jB = NC + 1;
      for (int w = 0; w < 16; ++w) { jA = min(jA, ired[w]); jB = min(jB, ired2[w]); }
      int nfire, clampLast;
      if (jB < jA) { nfire = jB - j0 + 1; clampLast = 1; }
      else         { nfire = jA - j0;     clampLast = 0; }
      if (nfire < 0) nfire = 0;
      int ntot = nst0 + nfire;
      if (ntot > MAXST) ntot = MAXST;
      pub_nfire = nfire; pub_clamp = clampLast; pub_ntot = ntot;
    }
    __syncthreads();
    int nfire = pub_nfire, clampLast = pub_clamp;
    for (int i = t; i < nfire; i += NT) {
      int idx = nst0 + i;
      if (idx < MAXST) {
        int y = ev[j0 + i].y;
        ws->states[idx] = make_int2(sbF, (clampLast && i == nfire - 1) ? sbF : y);
      }
    }
    if (t == 0) ws->n_states = pub_ntot;
  } else {
    if (t == 0) ws->n_states = nst0;
  }
}

// ---------------- Phase 3b: evaluate quantization error for all states ----------------
__global__ void __launch_bounds__(256) k_eval(Ws* __restrict__ ws) {
  int i = blockIdx.x;
  if (i >= ws->n_states) return;
  int2 st = ws->states[i];
  float bw = ws->bin_width;
  float cntf = (float)(st.y - st.x + 1);
  float w = bw * cntf / (float)DSTN;
  int t = threadIdx.x;
  if (w == 0.0f) {
    if (t == 0) ws->norms[i] = 0.0f;
    return;
  }
  float hw = 0.5f * w;
  float hw3 = hw * hw * hw;
  float nsb = (float)st.x;
  float sum = 0.0f;
  #pragma unroll
  for (int k = 0; k < 8; ++k) {
    int j = t + 256 * k;
    float h = ws->histf[j];
    float begin = ((float)j - nsb) * bw;
    float end = begin + bw;
    float db = fminf(fmaxf(floorf(begin / w), 0.0f), (float)(DSTN - 1));
    float de = fminf(fmaxf(floorf(end / w), 0.0f), (float)(DSTN - 1));
    float density = h / bw;
    float dbc = (db + 0.5f) * w;
    float a1 = begin - dbc;
    float n1 = density * (hw3 - a1 * a1 * a1) / 3.0f;
    float nmid = density * (hw3 + hw3) / 3.0f;
    float dec = de * w + hw;
    float a3 = end - dec;
    float n3 = density * (a3 * a3 * a3 + hw3) / 3.0f;
    sum += n1 + (de - db - 1.0f) * nmid + n3;
  }
  __shared__ float red[256];
  red[t] = sum;
  __syncthreads();
  for (int off = 128; off > 0; off >>= 1) {
    if (t < off) red[t] += red[t + off];
    __syncthreads();
  }
  if (t == 0) ws->norms[i] = red[0];
}

// ---------------- Phase 3c: first norm increase -> final range ----------------
__global__ void __launch_bounds__(256) k_final(Ws* __restrict__ ws, float* __restrict__ out) {
  __shared__ int sbrk[256];
  int N = ws->n_states;
  int t = threadIdx.x;
  int loc = MINF;
  for (int i = t + 1; i < N; i += 256) {
    if (ws->norms[i] > ws->norms[i - 1]) loc = min(loc, i);
  }
  sbrk[t] = loc;
  __syncthreads();
  for (int off = 128; off > 0; off >>= 1) {
    if (t < off) sbrk[t] = min(sbrk[t], sbrk[t + off]);
    __syncthreads();
  }
  if (t == 0) {
    int sb, eb;
    if (N == 0) { sb = 0; eb = BINS - 1; }
    else {
      int ib = sbrk[0];
      int fi = (ib != MINF) ? (ib - 1) : (N - 1);
      int2 st = ws->states[fi];
      sb = st.x; eb = st.y;
    }
    float minv = ws->min_val, bw = ws->bin_width;
    out[0] = minv + bw * (float)sb;
    out[1] = minv + bw * (float)(eb + 1);
  }
}

extern "C" void kernel_launch(void* const* d_in, const int* in_sizes, int n_in,
                              void* d_out, int out_size, void* d_ws, size_t ws_size,
                              hipStream_t stream) {
  const float* x = (const float*)d_in[0];
  long long n = (long long)in_sizes[0];
  Ws* ws = (Ws*)d_ws;
  float* out = (float*)d_out;

  k_tables<<<1, 256, 0, stream>>>(ws);
  k_minmax<<<NMM, 256, 0, stream>>>(x, n, ws);
  k_minmax_final<<<1, 256, 0, stream>>>(ws, NMM);
  k_hist<<<NHIST, 256, 0, stream>>>(x, n, ws);
  k_search<<<1, NT, 0, stream>>>(ws);
  k_eval<<<MAXST, 256, 0, stream>>>(ws);
  k_final<<<1, 256, 0, stream>>>(ws, out);
}

// Round 15
// 146.996 us; speedup vs baseline: 1.4972x; 1.0696x over previous
//
#include <hip/hip_runtime.h>
#include <float.h>
#include <math.h>

#define BINS 2048
#define DSTN 8
#define STEPF 1e-5f
#define NMM 1024          // minmax partial blocks (+1 table block)
#define NHIST 1024
#define MAXST 2048
#define NSEG 64
#define MINF 0x7fffffff
#define NT 1024           // k_search block size

struct Ws {
  int nseg, mbot;
  int n_states;
  int pad0[5];
  float min_val, max_val, bin_width, safe_bw;
  float pmin[NMM];
  float pmax[NMM];
  unsigned int hist[BINS];
  float histf[BINS];
  float Atab[2052];
  int   mterm[2052];
  int4  segB4[NSEG];
  float norms[MAXST];
  int2  states[MAXST];
};

// ---------------- Pass 1: block-partial min/max (blocks 0..NMM-1, round-1 structure,
// NO atomics/fences) + concurrent data-independent table build (block NMM) ----------------
__global__ void __launch_bounds__(256) k_minmax(const float* __restrict__ x, long long n,
                                                Ws* __restrict__ ws) {
  int t = threadIdx.x;
  const float S = STEPF;

  if (blockIdx.x == NMM) {
    // ======== data-independent tables (concurrent with the HBM sweep; validated r4-r14) ====
    __shared__ __align__(16) int4 sB4[NSEG], sA4[NSEG];
    __shared__ int segklo[NSEG];
    __shared__ int s_nsg, s_mbot, s_nsa;
    if (t == 0) {
      // ---- B binade-segment table ----
      int sg = 0; float B = 1.0f; int m0 = 0; int mbot = MINF;
      while (sg < NSEG && B > 0.0f) {
        float Bn = B - S;
        if (Bn <= 0.0f) {
          sB4[sg] = make_int4(__float_as_int(B), __float_as_int(B - Bn), m0, 0);
          ++sg; mbot = m0 + 1; break;
        }
        float d = B - Bn;                  // exact (Sterbenz)
        unsigned bb = __float_as_uint(B);
        unsigned bid = bb & 0x7f800000u;
        if ((bb & 0x007fffffu) == 0u) bid -= 0x00800000u;
        float binlo = __uint_as_float(bid);
        float brel = B - binlo;
        int nn = (int)floor((double)brel / (double)d);
        if (nn < 0) nn = 0;
        if (nn >= 2) {                     // tie-alternation guard
          float B1 = B - d;
          float B2 = B1 - S;
          if (B1 - B2 != d) nn = 1;
        }
        sB4[sg] = make_int4(__float_as_int(B), __float_as_int(d), m0, nn);
        ++sg;
        float Blast = B - (float)nn * d;
        B = Blast - S;
        m0 += nn + 1;
        if (B <= 0.0f) { mbot = m0; break; }
      }
      s_nsg = sg; s_mbot = mbot;
      // ---- A binade-segment table ----
      int sa = 0;
      sA4[sa++] = make_int4(__float_as_int(0.0f), __float_as_int(S), 0, 0);  // A[0]=0
      float A0 = S; int k0 = 1;
      while (sa < NSEG && k0 <= 2051) {
        float An = A0 + S;
        float d = An - A0;                 // exact
        unsigned ab = __float_as_uint(A0);
        unsigned abid = ab & 0x7f800000u;
        float binhi = __uint_as_float(abid + 0x00800000u);
        float brel = binhi - A0;
        int nn = (int)floorf(brel / d);
        if (nn < 0) nn = 0;
        while (nn >= 1 && !(A0 + (float)nn * d < binhi)) --nn;
        while (A0 + (float)(nn + 1) * d < binhi) ++nn;
        if (nn >= 2) {                     // tie-alternation guard
          float A1 = A0 + d;
          float A2 = A1 + S;
          if (A2 - A1 != d) nn = 1;
        }
        if (k0 + nn > 2051) nn = 2051 - k0;
        sA4[sa++] = make_int4(__float_as_int(A0), __float_as_int(d), k0, nn);
        float Alast = A0 + (float)nn * d;
        A0 = Alast + S;
        k0 += nn + 1;
      }
      s_nsa = sa;
    }
    __syncthreads();
    int nsg = s_nsg, mbot = s_mbot, nsa = s_nsa;

    for (int sg = 0; sg < nsa; ++sg) {
      int4 sv = sA4[sg];
      float A0v = __int_as_float(sv.x), dv = __int_as_float(sv.y);
      for (int i = t; i <= sv.w; i += 256) ws->Atab[sv.z + i] = A0v + (float)i * dv;
    }
    __syncthreads();
    {
      int okA = 1;
      for (int k = t; k < 2051; k += 256) okA &= (ws->Atab[k] + S == ws->Atab[k + 1]) ? 1 : 0;
      if (__syncthreads_and(okA) == 0) {
        if (t == 0) {
          float a = 0.0f; ws->Atab[0] = 0.0f;
          for (int k = 1; k < 2052; ++k) { a = a + S; ws->Atab[k] = a; }
        }
        __syncthreads();
      }
    }
    if (t < nsg) {
      int4 sv = sB4[t];
      float Bs = __int_as_float(sv.x), dd = __int_as_float(sv.y);
      float Bend = Bs - (float)sv.w * dd;
      int lo = 0, hi = 2052;
      while (lo < hi) { int mid = (lo + hi) >> 1; if (ws->Atab[mid] < Bend) lo = mid + 1; else hi = mid; }
      segklo[t] = lo;
      ws->segB4[t] = sv;
    }
    if (t == 0) { ws->nseg = nsg; ws->mbot = mbot; }
    __syncthreads();
    for (int sg = 0; sg < nsg; ++sg) {
      int lo = segklo[sg], hi = (sg ? segklo[sg - 1] : 2052);
      if (lo >= hi) continue;
      int4 sv = sB4[sg];
      float Bs = __int_as_float(sv.x), dd = __int_as_float(sv.y);
      int ms = sv.z, nn = sv.w;
      float rd = (dd > 0.0f) ? 1.0f / dd : 0.0f;
      for (int k = lo + t; k < hi; k += 256) {
        float a = ws->Atab[k];
        int i2 = (int)((Bs - a) * rd);
        if (i2 < 0) i2 = 0; if (i2 > nn) i2 = nn;
        while (i2 > 0 && Bs - (float)(i2 - 1) * dd <= a) --i2;
        while (i2 <= nn && Bs - (float)i2 * dd > a) ++i2;
        ws->mterm[k] = ms + i2;
      }
    }
    {
      int dhi = segklo[nsg - 1];
      for (int k = t; k < dhi; k += 256) ws->mterm[k] = mbot;
    }
    return;
  }

  // ======== min/max partial (blocks 0..NMM-1) ========
  long long n4 = n >> 2;
  float vmin = FLT_MAX, vmax = -FLT_MAX;
  const float4* __restrict__ x4 = (const float4*)x;
  long long stride = (long long)NMM * 256;
  for (long long i = (long long)blockIdx.x * 256 + t; i < n4; i += stride) {
    float4 v = x4[i];
    vmin = fminf(vmin, fminf(fminf(v.x, v.y), fminf(v.z, v.w)));
    vmax = fmaxf(vmax, fmaxf(fmaxf(v.x, v.y), fmaxf(v.z, v.w)));
  }
  for (long long i = (n4 << 2) + (long long)blockIdx.x * 256 + t; i < n; i += stride) {
    float v = x[i];
    vmin = fminf(vmin, v); vmax = fmaxf(vmax, v);
  }
  for (int off = 32; off > 0; off >>= 1) {
    vmin = fminf(vmin, __shfl_down(vmin, off));
    vmax = fmaxf(vmax, __shfl_down(vmax, off));
  }
  __shared__ float smin[4], smax[4];
  int wid = t >> 6;
  if ((t & 63) == 0) { smin[wid] = vmin; smax[wid] = vmax; }
  __syncthreads();
  if (t == 0) {
    float a = smin[0], b = smax[0];
    for (int w = 1; w < 4; ++w) { a = fminf(a, smin[w]); b = fmaxf(b, smax[w]); }
    ws->pmin[blockIdx.x] = a; ws->pmax[blockIdx.x] = b;
  }
}

// ---------------- Reduce partials, compute bin_width, zero hist ----------------
__global__ void __launch_bounds__(256) k_minmax_final(Ws* __restrict__ ws, int nparts) {
  __shared__ float smin[256], smax[256];
  int t = threadIdx.x;
  float vmin = FLT_MAX, vmax = -FLT_MAX;
  for (int i = t; i < nparts; i += 256) {
    vmin = fminf(vmin, ws->pmin[i]);
    vmax = fmaxf(vmax, ws->pmax[i]);
  }
  smin[t] = vmin; smax[t] = vmax;
  __syncthreads();
  for (int off = 128; off > 0; off >>= 1) {
    if (t < off) { smin[t] = fminf(smin[t], smin[t + off]); smax[t] = fmaxf(smax[t], smax[t + off]); }
    __syncthreads();
  }
  if (t == 0) {
    float mn = smin[0], mx = smax[0];
    ws->min_val = mn; ws->max_val = mx;
    float bw = (mx - mn) / (float)BINS;
    ws->bin_width = bw;
    ws->safe_bw = (bw == 0.0f) ? 1.0f : bw;
  }
  for (int i = t; i < BINS; i += 256) ws->hist[i] = 0u;
}

// ---------------- Pass 2: histogram — 4-way LDS sub-hists, exact /sbw, grid-stride ----
__global__ void __launch_bounds__(256) k_hist(const float* __restrict__ x, long long n,
                                              Ws* __restrict__ ws) {
  __shared__ __align__(16) unsigned int lh[BINS * 4];
  for (int i = threadIdx.x; i < BINS * 4; i += 256) lh[i] = 0u;
  __syncthreads();
  float minv = ws->min_val;
  float sbw = ws->safe_bw;
  int sub = threadIdx.x & 3;
  long long n4 = n >> 2;
  const float4* __restrict__ x4 = (const float4*)x;
  long long stride = (long long)gridDim.x * blockDim.x;
  for (long long i = (long long)blockIdx.x * blockDim.x + threadIdx.x; i < n4; i += stride) {
    float4 v = x4[i];
    int a = min(BINS - 1, max(0, (int)floorf((v.x - minv) / sbw)));
    int b = min(BINS - 1, max(0, (int)floorf((v.y - minv) / sbw)));
    int c = min(BINS - 1, max(0, (int)floorf((v.z - minv) / sbw)));
    int d = min(BINS - 1, max(0, (int)floorf((v.w - minv) / sbw)));
    atomicAdd(&lh[(a << 2) | sub], 1u);
    atomicAdd(&lh[(b << 2) | sub], 1u);
    atomicAdd(&lh[(c << 2) | sub], 1u);
    atomicAdd(&lh[(d << 2) | sub], 1u);
  }
  for (long long i = (n4 << 2) + (long long)blockIdx.x * blockDim.x + threadIdx.x; i < n; i += stride) {
    int a = (int)floorf((x[i] - minv) / sbw);
    a = min(BINS - 1, max(0, a));
    atomicAdd(&lh[(a << 2) | sub], 1u);
  }
  __syncthreads();
  for (int q = threadIdx.x; q < BINS; q += 256) {
    uint4 v = *((const uint4*)lh + q);
    unsigned int c = v.x + v.y + v.z + v.w;
    if (c) atomicAdd(&ws->hist[q], c);
  }
}

// ---------------- Phase 3a: csum-dependent tables + zipper + parallel tail ----
// (validated rounds 7-14; static tables prebuilt in k_minmax's table block)
__global__ void __launch_bounds__(NT) k_search(Ws* __restrict__ ws) {
  __shared__ __align__(16) float csum[BINS];
  __shared__ __align__(16) int2  ltmt[2052];
  __shared__ __align__(16) int   mcross[BINS];
  __shared__ __align__(16) int   chain[2052];
  __shared__ __align__(16) int2  ev[2049];
  __shared__ __align__(16) int4  sB4[NSEG];
  __shared__ int   segblo[NSEG];
  __shared__ float fwav[16];
  __shared__ int   ired[16], ired2[16];
  __shared__ int   pub_nc;
  __shared__ int   pub_mode, pub_j0, pub_sb, pub_mt, pub_nst0, pub_nfire, pub_clamp, pub_ntot;

  int t = threadIdx.x;
  int lane = t & 63, wid = t >> 6;

  if (t < NSEG) sB4[t] = ws->segB4[t];
  int nsg = ws->nseg;
  int mbot = ws->mbot;

  // ---- phase 0: cumsum (integer-exact under any association) ----
  float h0 = (float)ws->hist[2 * t];
  float h1 = (float)ws->hist[2 * t + 1];
  ws->histf[2 * t] = h0; ws->histf[2 * t + 1] = h1;
  float s = h0 + h1;
  float isc = s;
  #pragma unroll
  for (int off = 1; off < 64; off <<= 1) {
    float u = __shfl_up(isc, off);
    if (lane >= off) isc += u;
  }
  if (lane == 63) fwav[wid] = isc;
  __syncthreads();
  if (t < 16) {
    float v = fwav[t];
    #pragma unroll
    for (int off = 1; off < 16; off <<= 1) {
      float u = __shfl_up(v, off, 16);
      if ((t & 15) >= off) v += u;
    }
    fwav[t] = v;
  }
  __syncthreads();
  {
    float base = wid ? fwav[wid - 1] : 0.0f;
    float excl = base + (isc - s);
    csum[2 * t] = excl + h0;
    csum[2 * t + 1] = excl + s;
  }
  __syncthreads();

  const float T = csum[BINS - 1];
  const float rcpT = 1.0f / T;

  // ---- phase 2a: ltab binary searches (3-wide) + mterm load ----
  {
    int lov[3], hiv[3];
    float av1[3];
    #pragma unroll
    for (int i = 0; i < 3; ++i) {
      int k = t + NT * i;
      bool has = (k <= 2050);
      lov[i] = 0; hiv[i] = has ? BINS : 0;
      av1[i] = has ? ws->Atab[k + 1] * T : 0.0f;
    }
    #pragma unroll
    for (int lev = 0; lev < 12; ++lev) {
      #pragma unroll
      for (int i = 0; i < 3; ++i) {
        bool act = lov[i] < hiv[i];
        int mid = act ? ((lov[i] + hiv[i]) >> 1) : 0;
        float cv = csum[mid];
        bool g = act && (cv < av1[i]);
        lov[i] = g ? (mid + 1) : lov[i];
        hiv[i] = (act && !g) ? mid : hiv[i];
      }
    }
    #pragma unroll
    for (int i = 0; i < 3; ++i) {
      int k = t + NT * i;
      if (k < 2052) ltmt[k] = make_int2((k <= 2050) ? lov[i] : BINS, ws->mterm[k]);
    }
  }
  // ---- per-segment b-range bounds ----
  if (t < nsg) {
    int4 sv = sB4[t];
    float Bs = __int_as_float(sv.x), dd = __int_as_float(sv.y);
    float Bend = Bs - (float)sv.w * dd;
    float vt = Bend * T;
    int lo = 0, hi = BINS;
    while (lo < hi) { int mid = (lo + hi) >> 1; if (!(csum[mid] > vt)) lo = mid + 1; else hi = mid; }
    segblo[t] = lo;
  }
  __syncthreads();

  // ---- phase 2c: mcross via range inversion ----
  for (int sg = 0; sg < nsg; ++sg) {
    int lo = segblo[sg], hi = (sg ? segblo[sg - 1] : BINS);
    if (lo >= hi) continue;
    int4 sv = sB4[sg];
    float Bs = __int_as_float(sv.x), dd = __int_as_float(sv.y);
    int ms = sv.z, nn = sv.w;
    float rd = (dd > 0.0f) ? 1.0f / dd : 0.0f;
    for (int b = lo + t; b < hi; b += NT) {
      float c = csum[b];
      int i2 = (int)((Bs - c * rcpT) * rd);
      if (i2 < 0) i2 = 0; if (i2 > nn) i2 = nn;
      while (i2 > 0 && (Bs - (float)(i2 - 1) * dd) * T < c) --i2;
      while (i2 <= nn && !((Bs - (float)i2 * dd) * T < c)) ++i2;
      mcross[b] = ms + i2 - 1;
    }
  }
  {
    int dhi = segblo[nsg - 1];
    for (int b = t; b < dhi; b += NT) {
      float c = csum[b];
      mcross[b] = (c > 0.0f) ? ((mbot == MINF) ? MINF : (mbot - 1)) : MINF;
    }
  }
  __syncthreads();

  // ---- phase 3: run-endpoint ranks (wave-scan suffix count) + scatter chain ----
  {
    int b0 = 2 * t;
    int m0v = mcross[b0], m1v = mcross[b0 + 1];
    int mnext = (t < NT - 1) ? mcross[b0 + 2] : 0;
    bool e0b = (m0v != m1v);
    bool e1b = (b0 + 1 == BINS - 1) || (m1v != mnext);
    int cnt = (e0b ? 1 : 0) + (e1b ? 1 : 0);
    int inc = cnt;
    #pragma unroll
    for (int off = 1; off < 64; off <<= 1) {
      int u = __shfl_up(inc, off);
      if (lane >= off) inc += u;
    }
    if (lane == 63) ired[wid] = inc;
    __syncthreads();
    if (t < 16) {
      int v = ired[t];
      #pragma unroll
      for (int off = 1; off < 16; off <<= 1) {
        int u = __shfl_up(v, off, 16);
        if ((t & 15) >= off) v += u;
      }
      ired[t] = v;
    }
    __syncthreads();
    int base = wid ? ired[wid - 1] : 0;
    int incl_t = base + inc;
    int total = ired[15];
    int running = total - incl_t;
    if (e1b) { ++running; chain[running - 1] = b0 + 1; }
    if (e0b) { ++running; chain[running - 1] = b0; }
    if (t == 0) pub_nc = total;
  }
  __syncthreads();

  // ---- phase 4: parallel event list ----
  int NC = pub_nc;
  for (int j = 1 + t; j <= NC; j += NT) {
    ev[j] = make_int2(mcross[chain[j - 1]], (j < NC) ? chain[j] : -1);
  }
  if (t == 0 && NC < 2048) ev[NC + 1] = make_int2(MINF, -1);
  __syncthreads();

  // ---- phase 5: short serial zipper ----
  if (t == 0) {
    int k = 0, sb = 0, eb = BINS - 1, m = 0, j = 1, nst = 0;
    int2 lm0 = ltmt[0], lm1 = ltmt[1], lm2 = ltmt[2];
    int2 e0 = ev[1], e1 = ev[2], e2 = ev[3];
    int mode = 0;
    int guard = 0;
    pub_j0 = 0; pub_sb = 0; pub_mt = 0;
    while (++guard < 6000) {
      int lpos = lm0.x, mt = lm0.y;
      int mc = e0.x, ne = e0.y;
      int l = min(lpos, eb);
      int pl = l - sb;
      if (pl <= 0) { mode = 1; pub_j0 = j; pub_sb = sb; pub_mt = mt; break; }  // left frozen forever
      if (m >= mt) break;                               // alpha >= beta
      bool coin = (m == mc);
      int nec = max(ne, sb);
      int pr = eb - nec;
      bool fl = !coin || (pl > pr);
      if (fl) {
        sb = l; ++k;
        if (nst < MAXST) ws->states[nst] = make_int2(sb, eb);
        ++nst;
        if (sb >= eb) break;
        lm0 = lm1; lm1 = lm2; lm2 = ltmt[min(k + 2, 2051)];
      } else {
        eb = nec; m = mc + 1; ++j;
        if (nst < MAXST) ws->states[nst] = make_int2(sb, eb);
        ++nst;
        if (sb >= eb) break;
        e0 = e1; e1 = e2; e2 = ev[min(j + 2, 2048)];
      }
    }
    pub_mode = mode;
    pub_nst0 = (nst < MAXST) ? nst : MAXST;
  }
  __syncthreads();

  // ---- phase 6: parallel tail emission ----
  int mode = pub_mode;
  int nst0 = pub_nst0;
  if (mode == 1) {
    int j0 = pub_j0, sbF = pub_sb, mtF = pub_mt;
    int locA = NC + 1, locB = NC + 1;
    for (int j = j0 + t; j <= NC; j += NT) {
      int2 e = ev[j];
      if (e.x >= mtF && j < locA) locA = j;   // includes MINF sentinels
      if (e.y <= sbF && j < locB) locB = j;
    }
    #pragma unroll
    for (int off = 32; off > 0; off >>= 1) {
      locA = min(locA, __shfl_down(locA, off));
      locB = min(locB, __shfl_down(locB, off));
    }
    if (lane == 0) { ired[wid] = locA; ired2[wid] = locB; }
    __syncthreads();
    if (t == 0) {
      int jA = NC + 1, jB = NC + 1;
      for (int w = 0; w < 16; ++w) { jA = min(jA, ired[w]); jB = min(jB, ired2[w]); }
      int nfire, clampLast;
      if (jB < jA) { nfire = jB - j0 + 1; clampLast = 1; }
      else         { nfire = jA - j0;     clampLast = 0; }
      if (nfire < 0) nfire = 0;
      int ntot = nst0 + nfire;
      if (ntot > MAXST) ntot = MAXST;
      pub_nfire = nfire; pub_clamp = clampLast; pub_ntot = ntot;
    }
    __syncthreads();
    int nfire = pub_nfire, clampLast = pub_clamp;
    for (int i = t; i < nfire; i += NT) {
      int idx = nst0 + i;
      if (idx < MAXST) {
        int y = ev[j0 + i].y;
        ws->states[idx] = make_int2(sbF, (clampLast && i == nfire - 1) ? sbF : y);
      }
    }
    if (t == 0) ws->n_states = pub_ntot;
  } else {
    if (t == 0) ws->n_states = nst0;
  }
}

// ---------------- Phase 3b: evaluate quantization error for all states ----------------
__global__ void __launch_bounds__(256) k_eval(Ws* __restrict__ ws) {
  int i = blockIdx.x;
  if (i >= ws->n_states) return;
  int2 st = ws->states[i];
  float bw = ws->bin_width;
  float cntf = (float)(st.y - st.x + 1);
  float w = bw * cntf / (float)DSTN;
  int t = threadIdx.x;
  if (w == 0.0f) {
    if (t == 0) ws->norms[i] = 0.0f;
    return;
  }
  float hw = 0.5f * w;
  float hw3 = hw * hw * hw;
  float nsb = (float)st.x;
  float sum = 0.0f;
  #pragma unroll
  for (int k = 0; k < 8; ++k) {
    int j = t + 256 * k;
    float h = ws->histf[j];
    float begin = ((float)j - nsb) * bw;
    float end = begin + bw;
    float db = fminf(fmaxf(floorf(begin / w), 0.0f), (float)(DSTN - 1));
    float de = fminf(fmaxf(floorf(end / w), 0.0f), (float)(DSTN - 1));
    float density = h / bw;
    float dbc = (db + 0.5f) * w;
    float a1 = begin - dbc;
    float n1 = density * (hw3 - a1 * a1 * a1) / 3.0f;
    float nmid = density * (hw3 + hw3) / 3.0f;
    float dec = de * w + hw;
    float a3 = end - dec;
    float n3 = density * (a3 * a3 * a3 + hw3) / 3.0f;
    sum += n1 + (de - db - 1.0f) * nmid + n3;
  }
  __shared__ float red[256];
  red[t] = sum;
  __syncthreads();
  for (int off = 128; off > 0; off >>= 1) {
    if (t < off) red[t] += red[t + off];
    __syncthreads();
  }
  if (t == 0) ws->norms[i] = red[0];
}

// ---------------- Phase 3c: first norm increase -> final range ----------------
__global__ void __launch_bounds__(256) k_final(Ws* __restrict__ ws, float* __restrict__ out) {
  __shared__ int sbrk[256];
  int N = ws->n_states;
  int t = threadIdx.x;
  int loc = MINF;
  for (int i = t + 1; i < N; i += 256) {
    if (ws->norms[i] > ws->norms[i - 1]) loc = min(loc, i);
  }
  sbrk[t] = loc;
  __syncthreads();
  for (int off = 128; off > 0; off >>= 1) {
    if (t < off) sbrk[t] = min(sbrk[t], sbrk[t + off]);
    __syncthreads();
  }
  if (t == 0) {
    int sb, eb;
    if (N == 0) { sb = 0; eb = BINS - 1; }
    else {
      int ib = sbrk[0];
      int fi = (ib != MINF) ? (ib - 1) : (N - 1);
      int2 st = ws->states[fi];
      sb = st.x; eb = st.y;
    }
    float minv = ws->min_val, bw = ws->bin_width;
    out[0] = minv + bw * (float)sb;
    out[1] = minv + bw * (float)(eb + 1);
  }
}

extern "C" void kernel_launch(void* const* d_in, const int* in_sizes, int n_in,
                              void* d_out, int out_size, void* d_ws, size_t ws_size,
                              hipStream_t stream) {
  const float* x = (const float*)d_in[0];
  long long n = (long long)in_sizes[0];
  Ws* ws = (Ws*)d_ws;
  float* out = (float*)d_out;

  k_minmax<<<NMM + 1, 256, 0, stream>>>(x, n, ws);
  k_minmax_final<<<1, 256, 0, stream>>>(ws, NMM);
  k_hist<<<NHIST, 256, 0, stream>>>(x, n, ws);
  k_search<<<1, NT, 0, stream>>>(ws);
  k_eval<<<MAXST, 256, 0, stream>>>(ws);
  k_final<<<1, 256, 0, stream>>>(ws, out);
}

// Round 16
// 146.507 us; speedup vs baseline: 1.5022x; 1.0033x over previous
//
#include <hip/hip_runtime.h>
#include <float.h>
#include <math.h>

#define BINS 2048
#define DSTN 8
#define STEPF 1e-5f
#define NMM 1024          // minmax partial blocks (+1 table block)
#define NHIST 1024
#define MAXST 2048
#define NSEG 64
#define MINF 0x7fffffff
#define NT 1024           // k_search block size

struct Ws {
  int nseg, mbot;
  int n_states;
  int pad0[5];
  float min_val, max_val, bin_width, safe_bw;
  float pmin[NMM];
  float pmax[NMM];
  unsigned int hist[BINS];
  float Atab[2052];
  int   mterm[2052];
  int4  segB4[NSEG];
  float norms[MAXST];
  int2  states[MAXST];
};

// ---------------- Pass 1: block-partial min/max (blocks 0..NMM-1) +
// concurrent data-independent table build & hist zeroing (block NMM) ----------------
__global__ void __launch_bounds__(256) k_minmax(const float* __restrict__ x, long long n,
                                                Ws* __restrict__ ws) {
  int t = threadIdx.x;
  const float S = STEPF;

  if (blockIdx.x == NMM) {
    // ======== data-independent tables (concurrent with the HBM sweep; validated r4-r15) ====
    __shared__ __align__(16) int4 sB4[NSEG], sA4[NSEG];
    __shared__ int segklo[NSEG];
    __shared__ int s_nsg, s_mbot, s_nsa;
    // hist zero (consumed by k_hist next kernel — boundary orders it)
    for (int i = t; i < BINS; i += 256) ws->hist[i] = 0u;
    if (t == 0) {
      // ---- B binade-segment table ----
      int sg = 0; float B = 1.0f; int m0 = 0; int mbot = MINF;
      while (sg < NSEG && B > 0.0f) {
        float Bn = B - S;
        if (Bn <= 0.0f) {
          sB4[sg] = make_int4(__float_as_int(B), __float_as_int(B - Bn), m0, 0);
          ++sg; mbot = m0 + 1; break;
        }
        float d = B - Bn;                  // exact (Sterbenz)
        unsigned bb = __float_as_uint(B);
        unsigned bid = bb & 0x7f800000u;
        if ((bb & 0x007fffffu) == 0u) bid -= 0x00800000u;
        float binlo = __uint_as_float(bid);
        float brel = B - binlo;
        int nn = (int)floor((double)brel / (double)d);
        if (nn < 0) nn = 0;
        if (nn >= 2) {                     // tie-alternation guard
          float B1 = B - d;
          float B2 = B1 - S;
          if (B1 - B2 != d) nn = 1;
        }
        sB4[sg] = make_int4(__float_as_int(B), __float_as_int(d), m0, nn);
        ++sg;
        float Blast = B - (float)nn * d;
        B = Blast - S;
        m0 += nn + 1;
        if (B <= 0.0f) { mbot = m0; break; }
      }
      s_nsg = sg; s_mbot = mbot;
      // ---- A binade-segment table ----
      int sa = 0;
      sA4[sa++] = make_int4(__float_as_int(0.0f), __float_as_int(S), 0, 0);  // A[0]=0
      float A0 = S; int k0 = 1;
      while (sa < NSEG && k0 <= 2051) {
        float An = A0 + S;
        float d = An - A0;                 // exact
        unsigned ab = __float_as_uint(A0);
        unsigned abid = ab & 0x7f800000u;
        float binhi = __uint_as_float(abid + 0x00800000u);
        float brel = binhi - A0;
        int nn = (int)floorf(brel / d);
        if (nn < 0) nn = 0;
        while (nn >= 1 && !(A0 + (float)nn * d < binhi)) --nn;
        while (A0 + (float)(nn + 1) * d < binhi) ++nn;
        if (nn >= 2) {                     // tie-alternation guard
          float A1 = A0 + d;
          float A2 = A1 + S;
          if (A2 - A1 != d) nn = 1;
        }
        if (k0 + nn > 2051) nn = 2051 - k0;
        sA4[sa++] = make_int4(__float_as_int(A0), __float_as_int(d), k0, nn);
        float Alast = A0 + (float)nn * d;
        A0 = Alast + S;
        k0 += nn + 1;
      }
      s_nsa = sa;
    }
    __syncthreads();
    int nsg = s_nsg, mbot = s_mbot, nsa = s_nsa;

    for (int sg = 0; sg < nsa; ++sg) {
      int4 sv = sA4[sg];
      float A0v = __int_as_float(sv.x), dv = __int_as_float(sv.y);
      for (int i = t; i <= sv.w; i += 256) ws->Atab[sv.z + i] = A0v + (float)i * dv;
    }
    __syncthreads();
    {
      int okA = 1;
      for (int k = t; k < 2051; k += 256) okA &= (ws->Atab[k] + S == ws->Atab[k + 1]) ? 1 : 0;
      if (__syncthreads_and(okA) == 0) {
        if (t == 0) {
          float a = 0.0f; ws->Atab[0] = 0.0f;
          for (int k = 1; k < 2052; ++k) { a = a + S; ws->Atab[k] = a; }
        }
        __syncthreads();
      }
    }
    if (t < nsg) {
      int4 sv = sB4[t];
      float Bs = __int_as_float(sv.x), dd = __int_as_float(sv.y);
      float Bend = Bs - (float)sv.w * dd;
      int lo = 0, hi = 2052;
      while (lo < hi) { int mid = (lo + hi) >> 1; if (ws->Atab[mid] < Bend) lo = mid + 1; else hi = mid; }
      segklo[t] = lo;
      ws->segB4[t] = sv;
    }
    if (t == 0) { ws->nseg = nsg; ws->mbot = mbot; }
    __syncthreads();
    for (int sg = 0; sg < nsg; ++sg) {
      int lo = segklo[sg], hi = (sg ? segklo[sg - 1] : 2052);
      if (lo >= hi) continue;
      int4 sv = sB4[sg];
      float Bs = __int_as_float(sv.x), dd = __int_as_float(sv.y);
      int ms = sv.z, nn = sv.w;
      float rd = (dd > 0.0f) ? 1.0f / dd : 0.0f;
      for (int k = lo + t; k < hi; k += 256) {
        float a = ws->Atab[k];
        int i2 = (int)((Bs - a) * rd);
        if (i2 < 0) i2 = 0; if (i2 > nn) i2 = nn;
        while (i2 > 0 && Bs - (float)(i2 - 1) * dd <= a) --i2;
        while (i2 <= nn && Bs - (float)i2 * dd > a) ++i2;
        ws->mterm[k] = ms + i2;
      }
    }
    {
      int dhi = segklo[nsg - 1];
      for (int k = t; k < dhi; k += 256) ws->mterm[k] = mbot;
    }
    return;
  }

  // ======== min/max partial (blocks 0..NMM-1) ========
  long long n4 = n >> 2;
  float vmin = FLT_MAX, vmax = -FLT_MAX;
  const float4* __restrict__ x4 = (const float4*)x;
  long long stride = (long long)NMM * 256;
  for (long long i = (long long)blockIdx.x * 256 + t; i < n4; i += stride) {
    float4 v = x4[i];
    vmin = fminf(vmin, fminf(fminf(v.x, v.y), fminf(v.z, v.w)));
    vmax = fmaxf(vmax, fmaxf(fmaxf(v.x, v.y), fmaxf(v.z, v.w)));
  }
  for (long long i = (n4 << 2) + (long long)blockIdx.x * 256 + t; i < n; i += stride) {
    float v = x[i];
    vmin = fminf(vmin, v); vmax = fmaxf(vmax, v);
  }
  for (int off = 32; off > 0; off >>= 1) {
    vmin = fminf(vmin, __shfl_down(vmin, off));
    vmax = fmaxf(vmax, __shfl_down(vmax, off));
  }
  __shared__ float smin[4], smax[4];
  int wid = t >> 6;
  if ((t & 63) == 0) { smin[wid] = vmin; smax[wid] = vmax; }
  __syncthreads();
  if (t == 0) {
    float a = smin[0], b = smax[0];
    for (int w = 1; w < 4; ++w) { a = fminf(a, smin[w]); b = fmaxf(b, smax[w]); }
    ws->pmin[blockIdx.x] = a; ws->pmax[blockIdx.x] = b;
  }
}

// ---------------- Pass 2: histogram. Each block redundantly reduces the partials
// (deterministic identical order -> identical fp32 min/max per block), then 4-way
// LDS sub-hists with exact /sbw division. Block 0 publishes min/bin_width. ----------------
__global__ void __launch_bounds__(256) k_hist(const float* __restrict__ x, long long n,
                                              Ws* __restrict__ ws) {
  __shared__ __align__(16) unsigned int lh[BINS * 4];
  __shared__ float smin[256], smax[256];
  int t = threadIdx.x;
  // redundant per-block min/max reduce (same order in every block)
  {
    float vmin = FLT_MAX, vmax = -FLT_MAX;
    #pragma unroll
    for (int i = 0; i < NMM / 256; ++i) {
      vmin = fminf(vmin, ws->pmin[t + 256 * i]);
      vmax = fmaxf(vmax, ws->pmax[t + 256 * i]);
    }
    smin[t] = vmin; smax[t] = vmax;
  }
  for (int i = t; i < BINS * 4; i += 256) lh[i] = 0u;
  __syncthreads();
  for (int off = 128; off > 0; off >>= 1) {
    if (t < off) { smin[t] = fminf(smin[t], smin[t + off]); smax[t] = fmaxf(smax[t], smax[t + off]); }
    __syncthreads();
  }
  float minv = smin[0];
  float bw = (smax[0] - minv) / (float)BINS;
  float sbw = (bw == 0.0f) ? 1.0f : bw;
  if (blockIdx.x == 0 && t == 0) {
    ws->min_val = minv; ws->max_val = smax[0];
    ws->bin_width = bw; ws->safe_bw = sbw;
  }
  __syncthreads();

  int sub = t & 3;
  long long n4 = n >> 2;
  const float4* __restrict__ x4 = (const float4*)x;
  long long stride = (long long)gridDim.x * blockDim.x;
  for (long long i = (long long)blockIdx.x * blockDim.x + t; i < n4; i += stride) {
    float4 v = x4[i];
    int a = min(BINS - 1, max(0, (int)floorf((v.x - minv) / sbw)));
    int b = min(BINS - 1, max(0, (int)floorf((v.y - minv) / sbw)));
    int c = min(BINS - 1, max(0, (int)floorf((v.z - minv) / sbw)));
    int d = min(BINS - 1, max(0, (int)floorf((v.w - minv) / sbw)));
    atomicAdd(&lh[(a << 2) | sub], 1u);
    atomicAdd(&lh[(b << 2) | sub], 1u);
    atomicAdd(&lh[(c << 2) | sub], 1u);
    atomicAdd(&lh[(d << 2) | sub], 1u);
  }
  for (long long i = (n4 << 2) + (long long)blockIdx.x * blockDim.x + t; i < n; i += stride) {
    int a = (int)floorf((x[i] - minv) / sbw);
    a = min(BINS - 1, max(0, a));
    atomicAdd(&lh[(a << 2) | sub], 1u);
  }
  __syncthreads();
  for (int q = t; q < BINS; q += 256) {
    uint4 v = *((const uint4*)lh + q);
    unsigned int c = v.x + v.y + v.z + v.w;
    if (c) atomicAdd(&ws->hist[q], c);
  }
}

// ---------------- Phase 3a: csum-dependent tables + zipper + parallel tail ----
// (validated rounds 7-15; static tables prebuilt in k_minmax's table block)
__global__ void __launch_bounds__(NT) k_search(Ws* __restrict__ ws) {
  __shared__ __align__(16) float csum[BINS];
  __shared__ __align__(16) int2  ltmt[2052];
  __shared__ __align__(16) int   mcross[BINS];
  __shared__ __align__(16) int   chain[2052];
  __shared__ __align__(16) int2  ev[2049];
  __shared__ __align__(16) int4  sB4[NSEG];
  __shared__ int   segblo[NSEG];
  __shared__ float fwav[16];
  __shared__ int   ired[16], ired2[16];
  __shared__ int   pub_nc;
  __shared__ int   pub_mode, pub_j0, pub_sb, pub_mt, pub_nst0, pub_nfire, pub_clamp, pub_ntot;

  int t = threadIdx.x;
  int lane = t & 63, wid = t >> 6;

  if (t < NSEG) sB4[t] = ws->segB4[t];
  int nsg = ws->nseg;
  int mbot = ws->mbot;

  // ---- phase 0: cumsum (integer-exact under any association) ----
  float h0 = (float)ws->hist[2 * t];
  float h1 = (float)ws->hist[2 * t + 1];
  float s = h0 + h1;
  float isc = s;
  #pragma unroll
  for (int off = 1; off < 64; off <<= 1) {
    float u = __shfl_up(isc, off);
    if (lane >= off) isc += u;
  }
  if (lane == 63) fwav[wid] = isc;
  __syncthreads();
  if (t < 16) {
    float v = fwav[t];
    #pragma unroll
    for (int off = 1; off < 16; off <<= 1) {
      float u = __shfl_up(v, off, 16);
      if ((t & 15) >= off) v += u;
    }
    fwav[t] = v;
  }
  __syncthreads();
  {
    float base = wid ? fwav[wid - 1] : 0.0f;
    float excl = base + (isc - s);
    csum[2 * t] = excl + h0;
    csum[2 * t + 1] = excl + s;
  }
  __syncthreads();

  const float T = csum[BINS - 1];
  const float rcpT = 1.0f / T;

  // ---- phase 2a: ltab binary searches (3-wide) + mterm load ----
  {
    int lov[3], hiv[3];
    float av1[3];
    #pragma unroll
    for (int i = 0; i < 3; ++i) {
      int k = t + NT * i;
      bool has = (k <= 2050);
      lov[i] = 0; hiv[i] = has ? BINS : 0;
      av1[i] = has ? ws->Atab[k + 1] * T : 0.0f;
    }
    #pragma unroll
    for (int lev = 0; lev < 12; ++lev) {
      #pragma unroll
      for (int i = 0; i < 3; ++i) {
        bool act = lov[i] < hiv[i];
        int mid = act ? ((lov[i] + hiv[i]) >> 1) : 0;
        float cv = csum[mid];
        bool g = act && (cv < av1[i]);
        lov[i] = g ? (mid + 1) : lov[i];
        hiv[i] = (act && !g) ? mid : hiv[i];
      }
    }
    #pragma unroll
    for (int i = 0; i < 3; ++i) {
      int k = t + NT * i;
      if (k < 2052) ltmt[k] = make_int2((k <= 2050) ? lov[i] : BINS, ws->mterm[k]);
    }
  }
  // ---- per-segment b-range bounds ----
  if (t < nsg) {
    int4 sv = sB4[t];
    float Bs = __int_as_float(sv.x), dd = __int_as_float(sv.y);
    float Bend = Bs - (float)sv.w * dd;
    float vt = Bend * T;
    int lo = 0, hi = BINS;
    while (lo < hi) { int mid = (lo + hi) >> 1; if (!(csum[mid] > vt)) lo = mid + 1; else hi = mid; }
    segblo[t] = lo;
  }
  __syncthreads();

  // ---- phase 2c: mcross via range inversion ----
  for (int sg = 0; sg < nsg; ++sg) {
    int lo = segblo[sg], hi = (sg ? segblo[sg - 1] : BINS);
    if (lo >= hi) continue;
    int4 sv = sB4[sg];
    float Bs = __int_as_float(sv.x), dd = __int_as_float(sv.y);
    int ms = sv.z, nn = sv.w;
    float rd = (dd > 0.0f) ? 1.0f / dd : 0.0f;
    for (int b = lo + t; b < hi; b += NT) {
      float c = csum[b];
      int i2 = (int)((Bs - c * rcpT) * rd);
      if (i2 < 0) i2 = 0; if (i2 > nn) i2 = nn;
      while (i2 > 0 && (Bs - (float)(i2 - 1) * dd) * T < c) --i2;
      while (i2 <= nn && !((Bs - (float)i2 * dd) * T < c)) ++i2;
      mcross[b] = ms + i2 - 1;
    }
  }
  {
    int dhi = segblo[nsg - 1];
    for (int b = t; b < dhi; b += NT) {
      float c = csum[b];
      mcross[b] = (c > 0.0f) ? ((mbot == MINF) ? MINF : (mbot - 1)) : MINF;
    }
  }
  __syncthreads();

  // ---- phase 3: run-endpoint ranks (wave-scan suffix count) + scatter chain ----
  {
    int b0 = 2 * t;
    int m0v = mcross[b0], m1v = mcross[b0 + 1];
    int mnext = (t < NT - 1) ? mcross[b0 + 2] : 0;
    bool e0b = (m0v != m1v);
    bool e1b = (b0 + 1 == BINS - 1) || (m1v != mnext);
    int cnt = (e0b ? 1 : 0) + (e1b ? 1 : 0);
    int inc = cnt;
    #pragma unroll
    for (int off = 1; off < 64; off <<= 1) {
      int u = __shfl_up(inc, off);
      if (lane >= off) inc += u;
    }
    if (lane == 63) ired[wid] = inc;
    __syncthreads();
    if (t < 16) {
      int v = ired[t];
      #pragma unroll
      for (int off = 1; off < 16; off <<= 1) {
        int u = __shfl_up(v, off, 16);
        if ((t & 15) >= off) v += u;
      }
      ired[t] = v;
    }
    __syncthreads();
    int base = wid ? ired[wid - 1] : 0;
    int incl_t = base + inc;
    int total = ired[15];
    int running = total - incl_t;
    if (e1b) { ++running; chain[running - 1] = b0 + 1; }
    if (e0b) { ++running; chain[running - 1] = b0; }
    if (t == 0) pub_nc = total;
  }
  __syncthreads();

  // ---- phase 4: parallel event list ----
  int NC = pub_nc;
  for (int j = 1 + t; j <= NC; j += NT) {
    ev[j] = make_int2(mcross[chain[j - 1]], (j < NC) ? chain[j] : -1);
  }
  if (t == 0 && NC < 2048) ev[NC + 1] = make_int2(MINF, -1);
  __syncthreads();

  // ---- phase 5: short serial zipper ----
  if (t == 0) {
    int k = 0, sb = 0, eb = BINS - 1, m = 0, j = 1, nst = 0;
    int2 lm0 = ltmt[0], lm1 = ltmt[1], lm2 = ltmt[2];
    int2 e0 = ev[1], e1 = ev[2], e2 = ev[3];
    int mode = 0;
    int guard = 0;
    pub_j0 = 0; pub_sb = 0; pub_mt = 0;
    while (++guard < 6000) {
      int lpos = lm0.x, mt = lm0.y;
      int mc = e0.x, ne = e0.y;
      int l = min(lpos, eb);
      int pl = l - sb;
      if (pl <= 0) { mode = 1; pub_j0 = j; pub_sb = sb; pub_mt = mt; break; }  // left frozen forever
      if (m >= mt) break;                               // alpha >= beta
      bool coin = (m == mc);
      int nec = max(ne, sb);
      int pr = eb - nec;
      bool fl = !coin || (pl > pr);
      if (fl) {
        sb = l; ++k;
        if (nst < MAXST) ws->states[nst] = make_int2(sb, eb);
        ++nst;
        if (sb >= eb) break;
        lm0 = lm1; lm1 = lm2; lm2 = ltmt[min(k + 2, 2051)];
      } else {
        eb = nec; m = mc + 1; ++j;
        if (nst < MAXST) ws->states[nst] = make_int2(sb, eb);
        ++nst;
        if (sb >= eb) break;
        e0 = e1; e1 = e2; e2 = ev[min(j + 2, 2048)];
      }
    }
    pub_mode = mode;
    pub_nst0 = (nst < MAXST) ? nst : MAXST;
  }
  __syncthreads();

  // ---- phase 6: parallel tail emission ----
  int mode = pub_mode;
  int nst0 = pub_nst0;
  if (mode == 1) {
    int j0 = pub_j0, sbF = pub_sb, mtF = pub_mt;
    int locA = NC + 1, locB = NC + 1;
    for (int j = j0 + t; j <= NC; j += NT) {
      int2 e = ev[j];
      if (e.x >= mtF && j < locA) locA = j;   // includes MINF sentinels
      if (e.y <= sbF && j < locB) locB = j;
    }
    #pragma unroll
    for (int off = 32; off > 0; off >>= 1) {
      locA = min(locA, __shfl_down(locA, off));
      locB = min(locB, __shfl_down(locB, off));
    }
    if (lane == 0) { ired[wid] = locA; ired2[wid] = locB; }
    __syncthreads();
    if (t == 0) {
      int jA = NC + 1, jB = NC + 1;
      for (int w = 0; w < 16; ++w) { jA = min(jA, ired[w]); jB = min(jB, ired2[w]); }
      int nfire, clampLast;
      if (jB < jA) { nfire = jB - j0 + 1; clampLast = 1; }
      else         { nfire = jA - j0;     clampLast = 0; }
      if (nfire < 0) nfire = 0;
      int ntot = nst0 + nfire;
      if (ntot > MAXST) ntot = MAXST;
      pub_nfire = nfire; pub_clamp = clampLast; pub_ntot = ntot;
    }
    __syncthreads();
    int nfire = pub_nfire, clampLast = pub_clamp;
    for (int i = t; i < nfire; i += NT) {
      int idx = nst0 + i;
      if (idx < MAXST) {
        int y = ev[j0 + i].y;
        ws->states[idx] = make_int2(sbF, (clampLast && i == nfire - 1) ? sbF : y);
      }
    }
    if (t == 0) ws->n_states = pub_ntot;
  } else {
    if (t == 0) ws->n_states = nst0;
  }
}

// ---------------- Phase 3b: evaluate quantization error for all states ----------------
__global__ void __launch_bounds__(256) k_eval(Ws* __restrict__ ws) {
  int i = blockIdx.x;
  if (i >= ws->n_states) return;
  int2 st = ws->states[i];
  float bw = ws->bin_width;
  float cntf = (float)(st.y - st.x + 1);
  float w = bw * cntf / (float)DSTN;
  int t = threadIdx.x;
  if (w == 0.0f) {
    if (t == 0) ws->norms[i] = 0.0f;
    return;
  }
  float hw = 0.5f * w;
  float hw3 = hw * hw * hw;
  float nsb = (float)st.x;
  float sum = 0.0f;
  #pragma unroll
  for (int k = 0; k < 8; ++k) {
    int j = t + 256 * k;
    float h = (float)ws->hist[j];        // == histf[j] bit-exactly
    float begin = ((float)j - nsb) * bw;
    float end = begin + bw;
    float db = fminf(fmaxf(floorf(begin / w), 0.0f), (float)(DSTN - 1));
    float de = fminf(fmaxf(floorf(end / w), 0.0f), (float)(DSTN - 1));
    float density = h / bw;
    float dbc = (db + 0.5f) * w;
    float a1 = begin - dbc;
    float n1 = density * (hw3 - a1 * a1 * a1) / 3.0f;
    float nmid = density * (hw3 + hw3) / 3.0f;
    float dec = de * w + hw;
    float a3 = end - dec;
    float n3 = density * (a3 * a3 * a3 + hw3) / 3.0f;
    sum += n1 + (de - db - 1.0f) * nmid + n3;
  }
  __shared__ float red[256];
  red[t] = sum;
  __syncthreads();
  for (int off = 128; off > 0; off >>= 1) {
    if (t < off) red[t] += red[t + off];
    __syncthreads();
  }
  if (t == 0) ws->norms[i] = red[0];
}

// ---------------- Phase 3c: first norm increase -> final range ----------------
__global__ void __launch_bounds__(256) k_final(Ws* __restrict__ ws, float* __restrict__ out) {
  __shared__ int sbrk[256];
  int N = ws->n_states;
  int t = threadIdx.x;
  int loc = MINF;
  for (int i = t + 1; i < N; i += 256) {
    if (ws->norms[i] > ws->norms[i - 1]) loc = min(loc, i);
  }
  sbrk[t] = loc;
  __syncthreads();
  for (int off = 128; off > 0; off >>= 1) {
    if (t < off) sbrk[t] = min(sbrk[t], sbrk[t + off]);
    __syncthreads();
  }
  if (t == 0) {
    int sb, eb;
    if (N == 0) { sb = 0; eb = BINS - 1; }
    else {
      int ib = sbrk[0];
      int fi = (ib != MINF) ? (ib - 1) : (N - 1);
      int2 st = ws->states[fi];
      sb = st.x; eb = st.y;
    }
    float minv = ws->min_val, bw = ws->bin_width;
    out[0] = minv + bw * (float)sb;
    out[1] = minv + bw * (float)(eb + 1);
  }
}

extern "C" void kernel_launch(void* const* d_in, const int* in_sizes, int n_in,
                              void* d_out, int out_size, void* d_ws, size_t ws_size,
                              hipStream_t stream) {
  const float* x = (const float*)d_in[0];
  long long n = (long long)in_sizes[0];
  Ws* ws = (Ws*)d_ws;
  float* out = (float*)d_out;

  k_minmax<<<NMM + 1, 256, 0, stream>>>(x, n, ws);
  k_hist<<<NHIST, 256, 0, stream>>>(x, n, ws);
  k_search<<<1, NT, 0, stream>>>(ws);
  k_eval<<<MAXST, 256, 0, stream>>>(ws);
  k_final<<<1, 256, 0, stream>>>(ws, out);
}